// Round 1
// 94.862 us; speedup vs baseline: 1.0799x; 1.0799x over previous
//
#include <hip/hip_runtime.h>
#include <math.h>

#define TSTEPS 48
#define FEAT 60
#define BATCH 128
#define BLOCK 256
#define TWO_PI_F 6.2831853071795864769f

// R11: algebraic restructure of the hidden recurrence.
// Hidden 5-qubit map:  h'_m = Tr(G_m * tensor_q rho_q(h_q))
//   rho_q = 1/2 (I + cos h_q * Zt_q + sin h_q * (-Yt_q)),  Zt=U1 sz U1^, Yt=U1 sy U1^
//   G_m   = V^ D_m V,   V = CRX2chain*(tensor U2)*CRX1chain   (fixed per launch)
// => h'_m = sum_{sigma in {I,Z,Y}^5} coef[m][sigma] * prod_q {1,cos h_q,sin h_q}[sigma_q]
// coef (5x243) precomputed per block in LDS (phases A-D, all 256 threads),
// then the 48-step loop is one wave: 10 trig + depth-2 select + depth-3 product
// + 4-term dot + DPP butterfly/row_bcast reduce.  Critical path ~25 ops/step.

struct Cf { float r, i; };
__device__ __forceinline__ Cf cmul(Cf a, Cf b){ return {a.r*b.r - a.i*b.i, a.r*b.i + a.i*b.r}; }
__device__ __forceinline__ Cf cadd(Cf a, Cf b){ return {a.r+b.r, a.i+b.i}; }
__device__ __forceinline__ void mm2(const Cf A[4], const Cf B[4], Cf D[4]) {
  D[0] = cadd(cmul(A[0],B[0]), cmul(A[1],B[2]));
  D[1] = cadd(cmul(A[0],B[1]), cmul(A[1],B[3]));
  D[2] = cadd(cmul(A[2],B[0]), cmul(A[3],B[2]));
  D[3] = cadd(cmul(A[2],B[1]), cmul(A[3],B[3]));
}

// fused U = RZ * RY * RX from 3 consecutive params
__device__ __forceinline__ void fusedU(const float* p, Cf U[4]) {
  float cx = cosf(0.5f*p[0]), sxn = sinf(0.5f*p[0]);
  float cy = cosf(0.5f*p[1]), syn = sinf(0.5f*p[1]);
  float cz = cosf(0.5f*p[2]), szn = sinf(0.5f*p[2]);
  Cf RX[4] = {{cx,0.f},{0.f,-sxn},{0.f,-sxn},{cx,0.f}};
  Cf RY[4] = {{cy,0.f},{-syn,0.f},{syn,0.f},{cy,0.f}};
  Cf RZ[4] = {{cz,-szn},{0.f,0.f},{0.f,0.f},{cz,szn}};
  Cf M[4];
  mm2(RY, RX, M);
  mm2(RZ, M, U);
}

template<int CTRL>
__device__ __forceinline__ float dppf(float v) {
  return __int_as_float(__builtin_amdgcn_mov_dpp(__float_as_int(v), CTRL, 0xF, 0xF, true));
}

// xor-lane exchange within 16-lane rows (all DPP, verified lineage)
template<int M>
__device__ __forceinline__ float sx(float v) {
  if constexpr (M == 1)      return dppf<0xB1>(v);
  else if constexpr (M == 2) return dppf<0x4E>(v);
  else if constexpr (M == 3) return dppf<0x1B>(v);
  else if constexpr (M == 4) return dppf<0x141>(dppf<0x1B>(v));
  else                       return dppf<0x128>(v);   // M == 8
}

// full 64-lane sum -> broadcast via readlane(63).
// xor1..8 butterfly gives per-row sums in every lane; row_bcast15 (0x142) adds
// row0->row1, row2->row3; row_bcast31 (0x143) adds (row0+row1)->rows2,3.
__device__ __forceinline__ float wave_sum(float v) {
  v += sx<1>(v);
  v += sx<2>(v);
  v += sx<4>(v);
  v += sx<8>(v);
  v += dppf<0x142>(v);
  v += dppf<0x143>(v);
  return __int_as_float(__builtin_amdgcn_readlane(__float_as_int(v), 63));
}

__device__ __forceinline__ float2 conjmul(float2 a, float2 b) {
  // conj(a) * b
  return make_float2(a.x*b.x + a.y*b.y, a.x*b.y - a.y*b.x);
}

// contract one qubit: src = NT blocks of (2D)x(2D); dst = 3*NT blocks of DxD
// dst[((s*NT+t)*D+J)*D+K] = sum_{a,b} src[t][(2J+a)][(2K+b)] * P[s][b][a]
__device__ __forceinline__ void contract_q(const float2* __restrict__ src,
                                           float2* __restrict__ dst,
                                           const float2* __restrict__ Pq,
                                           int NT, int D, int tid) {
  const int total = 3*NT*D*D;
  const int bs = 2*D;
  for (int tau = tid; tau < total; tau += BLOCK) {
    int K = tau % D;
    int rr = tau / D;
    int J = rr % D; rr /= D;
    int t = rr % NT;
    int s2 = rr / NT;
    const float2* Sb = src + t*(bs*bs);
    const float2* Pm = Pq + s2*4;
    float ax = 0.f, ay = 0.f;
    #pragma unroll
    for (int a = 0; a < 2; ++a)
      #pragma unroll
      for (int bb = 0; bb < 2; ++bb) {
        float2 g = Sb[(2*J+a)*bs + (2*K+bb)];
        float2 p = Pm[bb*2 + a];
        ax += g.x*p.x - g.y*p.y;
        ay += g.x*p.y + g.y*p.x;
      }
    dst[tau] = make_float2(ax, ay);
  }
}

__global__ __launch_bounds__(BLOCK)
void qrnn_kernel(const float* __restrict__ x, const float* __restrict__ hin,
                 const float* __restrict__ params, float* __restrict__ out) {
  // ---- LDS layout (63.8 KB total, <64 KB) ----
  __shared__ float2 G5[5*1024];                    // 40960 B: G_m for all m
  __shared__ __align__(16) char uAV[16800];        // V (8 KB) overlaid by A1..A4
  __shared__ float coefL[5*256];                   // 5120 B (243 used, rest 0)
  __shared__ float2 Pl[5*12];                      // P[q][s][2x2], s in {I,Zt,-Yt}
  __shared__ float2 U2l[5*4];                      // layer-2 1q gates
  __shared__ float crxcl[8], crxsl[8];             // CRX half-angle cos/sin L1,L2
  __shared__ float Wl[6*8];                        // visible W = U2*U1

  const int b   = blockIdx.x;
  const int tid = threadIdx.x;

  float2* Vp = (float2*)uAV;
  float2* A1 = (float2*)uAV;                       // 3 x 16x16 (V dead by then)
  float2* A2 = (float2*)(uAV + 6144);              // 9 x 8x8
  float2* A3 = (float2*)(uAV + 10752);             // 27 x 4x4
  float2* A4 = (float2*)(uAV + 14208);             // 81 x 2x2

  // ================= Phase A: small fixed matrices (parallel) ==============
  if (tid < 5) {
    int q = tid;
    Cf U1[4]; fusedU(params + 3*q, U1);
    // U1 * sz  (negate column 1)
    Cf T[4] = {U1[0], {-U1[1].r,-U1[1].i}, U1[2], {-U1[3].r,-U1[3].i}};
    // U1^dagger (row-major)
    Cf Ud[4] = {{U1[0].r,-U1[0].i},{U1[2].r,-U1[2].i},
                {U1[1].r,-U1[1].i},{U1[3].r,-U1[3].i}};
    Cf Zt[4]; mm2(T, Ud, Zt);
    // U1 * sy : col0 = i*U1[:,1], col1 = -i*U1[:,0]
    Cf Ty[4] = {{-U1[1].i, U1[1].r}, {U1[0].i, -U1[0].r},
                {-U1[3].i, U1[3].r}, {U1[2].i, -U1[2].r}};
    Cf Yt[4]; mm2(Ty, Ud, Yt);
    float2* P = Pl + q*12;
    P[0] = make_float2(1.f,0.f); P[1] = make_float2(0.f,0.f);
    P[2] = make_float2(0.f,0.f); P[3] = make_float2(1.f,0.f);
    #pragma unroll
    for (int e = 0; e < 4; ++e) P[4+e] = make_float2(Zt[e].r, Zt[e].i);
    #pragma unroll
    for (int e = 0; e < 4; ++e) P[8+e] = make_float2(-Yt[e].r, -Yt[e].i);
  } else if (tid >= 8 && tid < 13) {
    int q = tid - 8;
    Cf U2[4]; fusedU(params + 37 + 3*q, U2);
    #pragma unroll
    for (int e = 0; e < 4; ++e) U2l[q*4+e] = make_float2(U2[e].r, U2[e].i);
  } else if (tid >= 16 && tid < 24) {
    int i = tid - 16;
    float th = (i < 4) ? params[15 + i] : params[52 + (i - 4)];
    crxcl[i] = cosf(0.5f*th); crxsl[i] = sinf(0.5f*th);
  } else if (tid >= 24 && tid < 30) {
    int k = tid - 24;
    Cf Ua[4], Ub[4], W[4];
    fusedU(params + 19 + 3*k, Ua);
    fusedU(params + 56 + 3*k, Ub);
    mm2(Ub, Ua, W);
    #pragma unroll
    for (int e = 0; e < 4; ++e) { Wl[k*8+2*e] = W[e].r; Wl[k*8+2*e+1] = W[e].i; }
  }
  __syncthreads();

  // ================= Phase B: build V (32x32) in LDS =======================
  for (int e = tid; e < 1024; e += BLOCK)
    Vp[e] = make_float2(((e >> 5) == (e & 31)) ? 1.f : 0.f, 0.f);
  __syncthreads();

  // L1 CRX chain (ctrl qubit g -> bit 4-g, target g+1 -> bit 3-g)
  #pragma unroll 1
  for (int g = 0; g < 4; ++g) {
    const int pt = 3 - g;
    const float hc = crxcl[g], hs = crxsl[g];
    for (int tau = tid; tau < 256; tau += BLOCK) {
      int col = tau & 31, pr = tau >> 5;
      int r0 = ((pr >> pt) << (pt+2)) | (1 << (pt+1)) | (pr & ((1 << pt) - 1));
      int r1 = r0 | (1 << pt);
      float2 a = Vp[r0*32+col], bb = Vp[r1*32+col];
      Vp[r0*32+col] = make_float2(hc*a.x + hs*bb.y, hc*a.y - hs*bb.x);
      Vp[r1*32+col] = make_float2(hs*a.y + hc*bb.x, -hs*a.x + hc*bb.y);
    }
    __syncthreads();
  }
  // L2 single-qubit gates
  #pragma unroll 1
  for (int q = 0; q < 5; ++q) {
    const int p = 4 - q;
    float2 u0 = U2l[q*4+0], u1 = U2l[q*4+1], u2 = U2l[q*4+2], u3 = U2l[q*4+3];
    for (int tau = tid; tau < 512; tau += BLOCK) {
      int col = tau & 31, pr = tau >> 5;
      int r0 = ((pr >> p) << (p+1)) | (pr & ((1 << p) - 1));
      int r1 = r0 | (1 << p);
      float2 a = Vp[r0*32+col], bb = Vp[r1*32+col];
      Vp[r0*32+col] = make_float2(u0.x*a.x - u0.y*a.y + u1.x*bb.x - u1.y*bb.y,
                                  u0.x*a.y + u0.y*a.x + u1.x*bb.y + u1.y*bb.x);
      Vp[r1*32+col] = make_float2(u2.x*a.x - u2.y*a.y + u3.x*bb.x - u3.y*bb.y,
                                  u2.x*a.y + u2.y*a.x + u3.x*bb.y + u3.y*bb.x);
    }
    __syncthreads();
  }
  // L2 CRX chain
  #pragma unroll 1
  for (int g = 0; g < 4; ++g) {
    const int pt = 3 - g;
    const float hc = crxcl[4+g], hs = crxsl[4+g];
    for (int tau = tid; tau < 256; tau += BLOCK) {
      int col = tau & 31, pr = tau >> 5;
      int r0 = ((pr >> pt) << (pt+2)) | (1 << (pt+1)) | (pr & ((1 << pt) - 1));
      int r1 = r0 | (1 << pt);
      float2 a = Vp[r0*32+col], bb = Vp[r1*32+col];
      Vp[r0*32+col] = make_float2(hc*a.x + hs*bb.y, hc*a.y - hs*bb.x);
      Vp[r1*32+col] = make_float2(hs*a.y + hc*bb.x, -hs*a.x + hc*bb.y);
    }
    __syncthreads();
  }

  // ================= Phase C: G_m = V^ D_m V (2x2 tile per thread) =========
  {
    const int jt = tid >> 4, kt = tid & 15;
    float2 acc[5][2][2];
    #pragma unroll
    for (int m = 0; m < 5; ++m)
      #pragma unroll
      for (int a = 0; a < 2; ++a)
        #pragma unroll
        for (int c2 = 0; c2 < 2; ++c2) acc[m][a][c2] = make_float2(0.f, 0.f);
    #pragma unroll 4
    for (int i = 0; i < 32; ++i) {
      float2 vj0 = Vp[i*32 + 2*jt], vj1 = Vp[i*32 + 2*jt + 1];
      float2 vk0 = Vp[i*32 + 2*kt], vk1 = Vp[i*32 + 2*kt + 1];
      float2 p00 = conjmul(vj0, vk0), p01 = conjmul(vj0, vk1);
      float2 p10 = conjmul(vj1, vk0), p11 = conjmul(vj1, vk1);
      #pragma unroll
      for (int m = 0; m < 5; ++m) {
        float sg = ((i >> (4 - m)) & 1) ? -1.f : 1.f;
        acc[m][0][0].x = fmaf(sg, p00.x, acc[m][0][0].x);
        acc[m][0][0].y = fmaf(sg, p00.y, acc[m][0][0].y);
        acc[m][0][1].x = fmaf(sg, p01.x, acc[m][0][1].x);
        acc[m][0][1].y = fmaf(sg, p01.y, acc[m][0][1].y);
        acc[m][1][0].x = fmaf(sg, p10.x, acc[m][1][0].x);
        acc[m][1][0].y = fmaf(sg, p10.y, acc[m][1][0].y);
        acc[m][1][1].x = fmaf(sg, p11.x, acc[m][1][1].x);
        acc[m][1][1].y = fmaf(sg, p11.y, acc[m][1][1].y);
      }
    }
    #pragma unroll
    for (int m = 0; m < 5; ++m)
      #pragma unroll
      for (int a = 0; a < 2; ++a)
        #pragma unroll
        for (int c2 = 0; c2 < 2; ++c2)
          G5[m*1024 + (2*jt + a)*32 + (2*kt + c2)] = acc[m][a][c2];
  }
  __syncthreads();

  // ================= Phase D: staged contraction -> coef[m][243] ===========
  #pragma unroll 1
  for (int m = 0; m < 5; ++m) {
    contract_q(G5 + m*1024, A1, Pl + 4*12, 1, 16, tid);   __syncthreads();
    contract_q(A1,          A2, Pl + 3*12, 3,  8, tid);   __syncthreads();
    contract_q(A2,          A3, Pl + 2*12, 9,  4, tid);   __syncthreads();
    contract_q(A3,          A4, Pl + 1*12, 27, 2, tid);   __syncthreads();
    for (int tau = tid; tau < 256; tau += BLOCK) {
      float val = 0.f;
      if (tau < 243) {
        int t = tau % 81, s2 = tau / 81;
        const float2* Sb = A4 + t*4;
        const float2* Pm = Pl + 0*12 + s2*4;
        float ax = 0.f;
        #pragma unroll
        for (int a = 0; a < 2; ++a)
          #pragma unroll
          for (int bb = 0; bb < 2; ++bb) {
            float2 g = Sb[a*2 + bb];
            float2 p = Pm[bb*2 + a];
            ax += g.x*p.x - g.y*p.y;
          }
        val = ax * (1.f/32.f);
      }
      coefL[m*256 + tau] = val;
    }
    __syncthreads();
  }

  // ================= main work =============================================
  const int w = tid >> 6, lane = tid & 63;
  if (w == 0) {
    // ---- hidden recurrence: 243-monomial polynomial map, 1 wave ----
    float sA[4][5], sB[4][5], sC[4][5], cf[5][4];
    #pragma unroll
    for (int j = 0; j < 4; ++j) {
      int n = j*64 + lane;
      int nn = (n < 243) ? n : 0;
      int d0 = nn/81; int rm = nn - d0*81;
      int d1 = rm/27; rm -= d1*27;
      int d2 = rm/9;  rm -= d2*9;
      int d3 = rm/3;  int d4 = rm - d3*3;
      int dq[5] = {d0, d1, d2, d3, d4};
      #pragma unroll
      for (int q = 0; q < 5; ++q) {
        sA[j][q] = (dq[q] == 0) ? 1.f : 0.f;
        sB[j][q] = (dq[q] == 1) ? 1.f : 0.f;
        sC[j][q] = (dq[q] == 2) ? 1.f : 0.f;
      }
      #pragma unroll
      for (int m = 0; m < 5; ++m) cf[m][j] = coefL[m*256 + n];
    }
    const float* hp = hin + b*5;
    float h0 = hp[0], h1 = hp[1], h2 = hp[2], h3 = hp[3], h4 = hp[4];
    #pragma unroll 1
    for (int t = 0; t < TSTEPS; ++t) {
      float cq0 = __cosf(h0), sq0 = __sinf(h0);
      float cq1 = __cosf(h1), sq1 = __sinf(h1);
      float cq2 = __cosf(h2), sq2 = __sinf(h2);
      float cq3 = __cosf(h3), sq3 = __sinf(h3);
      float cq4 = __cosf(h4), sq4 = __sinf(h4);
      float cq[5] = {cq0, cq1, cq2, cq3, cq4};
      float sq[5] = {sq0, sq1, sq2, sq3, sq4};
      float mono[4];
      #pragma unroll
      for (int j = 0; j < 4; ++j) {
        float f0 = fmaf(sB[j][0], cq[0], fmaf(sC[j][0], sq[0], sA[j][0]));
        float f1 = fmaf(sB[j][1], cq[1], fmaf(sC[j][1], sq[1], sA[j][1]));
        float f2 = fmaf(sB[j][2], cq[2], fmaf(sC[j][2], sq[2], sA[j][2]));
        float f3 = fmaf(sB[j][3], cq[3], fmaf(sC[j][3], sq[3], sA[j][3]));
        float f4 = fmaf(sB[j][4], cq[4], fmaf(sC[j][4], sq[4], sA[j][4]));
        mono[j] = ((f0*f1)*(f2*f3))*f4;
      }
      float hn[5];
      #pragma unroll
      for (int m = 0; m < 5; ++m) {
        float p01 = fmaf(cf[m][1], mono[1], cf[m][0]*mono[0]);
        float p23 = fmaf(cf[m][3], mono[3], cf[m][2]*mono[2]);
        hn[m] = wave_sum(p01 + p23);
      }
      h0 = hn[0]; h1 = hn[1]; h2 = hn[2]; h3 = hn[3]; h4 = hn[4];
    }
    if (lane < 5) {
      float hv = (lane==0) ? h0 : (lane==1) ? h1 : (lane==2) ? h2
               : (lane==3) ? h3 : h4;
      out[BATCH*TSTEPS*6 + b*5 + lane] = hv;
    }
  } else if (w == 1 && lane < TSTEPS) {
    // ---- visible outputs (pure function of x; W precomputed in LDS) ----
    const float* xp = x + (size_t)b*(TSTEPS*FEAT) + lane*FEAT;
    const float4* xp4 = (const float4*)xp;
    float4 vv[15];
    #pragma unroll
    for (int i2 = 0; i2 < 15; ++i2) vv[i2] = xp4[i2];
    float el[60];
    #pragma unroll
    for (int i2 = 0; i2 < 15; ++i2) {
      el[4*i2+0] = vv[i2].x; el[4*i2+1] = vv[i2].y;
      el[4*i2+2] = vv[i2].z; el[4*i2+3] = vv[i2].w;
    }
    float pooled[6];
    #pragma unroll
    for (int k = 0; k < 6; ++k) {
      float s = 0.f;
      #pragma unroll
      for (int f = 0; f < 10; ++f) s += el[k*10 + f];
      pooled[k] = s * 0.1f;
    }
    float mn = pooled[0], mx = pooled[0];
    #pragma unroll
    for (int v2 = 1; v2 < 6; ++v2) {
      mn = fminf(mn, pooled[v2]); mx = fmaxf(mx, pooled[v2]);
    }
    float* op = out + (size_t)b*(TSTEPS*6) + lane*6;
    #pragma unroll
    for (int k = 0; k < 6; ++k) {
      float W0r = Wl[k*8+0], W0i = Wl[k*8+1], W1r = Wl[k*8+2], W1i = Wl[k*8+3];
      float W2r = Wl[k*8+4], W2i = Wl[k*8+5], W3r = Wl[k*8+6], W3i = Wl[k*8+7];
      float ang = TWO_PI_F * (pooled[k] - mn) / (mx - mn + 1e-8f);
      float ch = __cosf(0.5f*ang), sh = __sinf(0.5f*ang);
      float v0r = W0r*ch + W1i*sh, v0i = W0i*ch - W1r*sh;
      float v1r = W2r*ch + W3i*sh, v1i = W2i*ch - W3r*sh;
      op[k] = (v0r*v0r + v0i*v0i) - (v1r*v1r + v1i*v1i);
    }
  }
}

extern "C" void kernel_launch(void* const* d_in, const int* in_sizes, int n_in,
                              void* d_out, int out_size, void* d_ws, size_t ws_size,
                              hipStream_t stream) {
  const float* x      = (const float*)d_in[0];
  const float* hidden = (const float*)d_in[1];
  const float* params = (const float*)d_in[2];
  float* out          = (float*)d_out;
  qrnn_kernel<<<dim3(BATCH), dim3(BLOCK), 0, stream>>>(x, hidden, params, out);
}

// Round 2
// 89.173 us; speedup vs baseline: 1.1488x; 1.0638x over previous
//
#include <hip/hip_runtime.h>
#include <math.h>

#define TSTEPS 48
#define FEAT 60
#define BATCH 128
#define BLOCK 256
#define TWO_PI_F 6.2831853071795864769f

// R12: setup restructure. Same math as R11 (coef[m][243] monomial recurrence),
// but: (1) V built by DPP gate application on 32 identity columns at once
// (zero barriers), (2) Phase C fused with contraction stage 1 (G never hits
// LDS), (3) all 5 m's contracted per stage.  38 barrier stages -> 7 barriers.

struct Cf { float r, i; };
__device__ __forceinline__ Cf cmul(Cf a, Cf b){ return {a.r*b.r - a.i*b.i, a.r*b.i + a.i*b.r}; }
__device__ __forceinline__ Cf cadd(Cf a, Cf b){ return {a.r+b.r, a.i+b.i}; }
__device__ __forceinline__ void mm2(const Cf A[4], const Cf B[4], Cf D[4]) {
  D[0] = cadd(cmul(A[0],B[0]), cmul(A[1],B[2]));
  D[1] = cadd(cmul(A[0],B[1]), cmul(A[1],B[3]));
  D[2] = cadd(cmul(A[2],B[0]), cmul(A[3],B[2]));
  D[3] = cadd(cmul(A[2],B[1]), cmul(A[3],B[3]));
}

// fused U = RZ * RY * RX from 3 consecutive params
__device__ __forceinline__ void fusedU(const float* p, Cf U[4]) {
  float cx = cosf(0.5f*p[0]), sxn = sinf(0.5f*p[0]);
  float cy = cosf(0.5f*p[1]), syn = sinf(0.5f*p[1]);
  float cz = cosf(0.5f*p[2]), szn = sinf(0.5f*p[2]);
  Cf RX[4] = {{cx,0.f},{0.f,-sxn},{0.f,-sxn},{cx,0.f}};
  Cf RY[4] = {{cy,0.f},{-syn,0.f},{syn,0.f},{cy,0.f}};
  Cf RZ[4] = {{cz,-szn},{0.f,0.f},{0.f,0.f},{cz,szn}};
  Cf M[4];
  mm2(RY, RX, M);
  mm2(RZ, M, U);
}

template<int CTRL>
__device__ __forceinline__ float dppf(float v) {
  return __int_as_float(__builtin_amdgcn_mov_dpp(__float_as_int(v), CTRL, 0xF, 0xF, true));
}

// xor-lane exchange within 16-lane rows (all DPP, verified lineage)
template<int M>
__device__ __forceinline__ float sx(float v) {
  if constexpr (M == 1)      return dppf<0xB1>(v);
  else if constexpr (M == 2) return dppf<0x4E>(v);
  else if constexpr (M == 3) return dppf<0x1B>(v);
  else if constexpr (M == 4) return dppf<0x141>(dppf<0x1B>(v));
  else                       return dppf<0x128>(v);   // M == 8
}

template<int M>
__device__ __forceinline__ Cf sxc(Cf v){ return { sx<M>(v.r), sx<M>(v.i) }; }

// full 64-lane sum -> broadcast via readlane(63)
__device__ __forceinline__ float wave_sum(float v) {
  v += sx<1>(v);
  v += sx<2>(v);
  v += sx<4>(v);
  v += sx<8>(v);
  v += dppf<0x142>(v);   // row_bcast15
  v += dppf<0x143>(v);   // row_bcast31
  return __int_as_float(__builtin_amdgcn_readlane(__float_as_int(v), 63));
}

__device__ __forceinline__ float2 conjmul(float2 a, float2 b) {
  return make_float2(a.x*b.x + a.y*b.y, a.x*b.y - a.y*b.x);   // conj(a)*b
}

// ---- V-build gate helpers (4 amps/thread: row = (quad<<2)|r, col = tid>>3) --
// 1q U on a LANE bit (xor distance M); hi = this lane's bit value
template<int M>
__device__ __forceinline__ void lane_u(Cf A[4], const Cf U[4], int hi) {
  Cf ca = hi ? U[3] : U[0];
  Cf cb = hi ? U[2] : U[1];
  #pragma unroll
  for (int r = 0; r < 4; ++r) {
    Cf o = sxc<M>(A[r]);
    A[r] = cadd(cmul(ca, A[r]), cmul(cb, o));
  }
}
// CRX with LANE target (xor M), lane-ctrl value cv: new = c*mine - i*s*other
template<int M>
__device__ __forceinline__ void lane_crx(Cf A[4], float c, float s, int cv) {
  float cc = cv ? c : 1.f, ss = cv ? s : 0.f;
  #pragma unroll
  for (int r = 0; r < 4; ++r) {
    Cf o = sxc<M>(A[r]);
    A[r] = { cc*A[r].r + ss*o.i, cc*A[r].i - ss*o.r };
  }
}
// 1q U on reg bit1: pairs (0,2),(1,3)
__device__ __forceinline__ void reg_u_b1(Cf A[4], const Cf U[4]) {
  #pragma unroll
  for (int k = 0; k < 2; ++k) {
    Cf a0 = A[k], a1 = A[k+2];
    A[k]   = cadd(cmul(U[0], a0), cmul(U[1], a1));
    A[k+2] = cadd(cmul(U[2], a0), cmul(U[3], a1));
  }
}
// 1q U on reg bit0: pairs (0,1),(2,3)
__device__ __forceinline__ void reg_u_b0(Cf A[4], const Cf U[4]) {
  #pragma unroll
  for (int k = 0; k < 4; k += 2) {
    Cf a0 = A[k], a1 = A[k+1];
    A[k]   = cadd(cmul(U[0], a0), cmul(U[1], a1));
    A[k+1] = cadd(cmul(U[2], a0), cmul(U[3], a1));
  }
}
// CRX target reg bit1, lane-ctrl value cv
__device__ __forceinline__ void reg_crx_b1(Cf A[4], float c, float s, int cv) {
  float cc = cv ? c : 1.f, ss = cv ? s : 0.f;
  #pragma unroll
  for (int k = 0; k < 2; ++k) {
    Cf a0 = A[k], a1 = A[k+2];
    A[k]   = { cc*a0.r + ss*a1.i, cc*a0.i - ss*a1.r };
    A[k+2] = { ss*a0.i + cc*a1.r, -ss*a0.r + cc*a1.i };
  }
}
// CRX target reg bit0, ctrl = reg bit1 (acts on regs 2,3 only)
__device__ __forceinline__ void reg_crx_b0c1(Cf A[4], float c, float s) {
  Cf a0 = A[2], a1 = A[3];
  A[2] = { c*a0.r + s*a1.i, c*a0.i - s*a1.r };
  A[3] = { s*a0.i + c*a1.r, -s*a0.r + c*a1.i };
}

// generic contraction stage over ALL m: peels current LSB qubit with P.
// src: (m*NTs + t) blocks of (2D)x(2D); dst[tau], tau=((m*3+s)*NTs+t)*D*D+J*D+K
template<int NTs, int D>
__device__ __forceinline__ void stageK(const float2* __restrict__ src,
                                       float2* __restrict__ dst,
                                       const float2* __restrict__ Pq, int tid) {
  const int total = 5*3*NTs*D*D;
  for (int tau = tid; tau < total; tau += BLOCK) {
    int K = tau % D;
    int J = (tau / D) % D;
    int rest = tau / (D*D);
    int t = rest % NTs;
    int s = (rest / NTs) % 3;
    int m = rest / (3*NTs);
    const float2* Sb = src + (m*NTs + t)*(4*D*D);
    const float2* Pm = Pq + s*4;
    float ax = 0.f, ay = 0.f;
    #pragma unroll
    for (int a = 0; a < 2; ++a)
      #pragma unroll
      for (int bb = 0; bb < 2; ++bb) {
        float2 g = Sb[(2*J+a)*(2*D) + (2*K+bb)];
        float2 p = Pm[bb*2 + a];
        ax += g.x*p.x - g.y*p.y;
        ay += g.x*p.y + g.y*p.x;
      }
    dst[tau] = make_float2(ax, ay);
  }
}

__global__ __launch_bounds__(BLOCK)
void qrnn_kernel(const float* __restrict__ x, const float* __restrict__ hin,
                 const float* __restrict__ params, float* __restrict__ out) {
  // ---- LDS (59.8 KB): two ping-pong buffers + tables ----
  __shared__ __align__(16) char bufA[30720];   // A1 (3840 f2) -> A3 (2160 f2)
  __shared__ __align__(16) char bufB[23040];   // V (1024 f2) -> A2 (2880) -> A4 (1620)
  __shared__ float coefL[5*256];
  __shared__ float2 Pl[5*12];                  // P[q][s][2x2], s in {I,Zt,-Yt}
  __shared__ float2 U2l[5*4];
  __shared__ float crxcl[8], crxsl[8];
  __shared__ float Wl[6*8];

  const int b   = blockIdx.x;
  const int tid = threadIdx.x;

  float2* Vp  = (float2*)bufB;
  float4* Vp4 = (float4*)bufB;
  float2* A1  = (float2*)bufA;
  float2* A2  = (float2*)bufB;
  float2* A3  = (float2*)bufA;
  float2* A4  = (float2*)bufB;

  // ================= Phase A: small fixed tables (parallel) ================
  if (tid < 5) {
    int q = tid;
    Cf U1[4]; fusedU(params + 3*q, U1);
    Cf T[4] = {U1[0], {-U1[1].r,-U1[1].i}, U1[2], {-U1[3].r,-U1[3].i}};
    Cf Ud[4] = {{U1[0].r,-U1[0].i},{U1[2].r,-U1[2].i},
                {U1[1].r,-U1[1].i},{U1[3].r,-U1[3].i}};
    Cf Zt[4]; mm2(T, Ud, Zt);
    Cf Ty[4] = {{-U1[1].i, U1[1].r}, {U1[0].i, -U1[0].r},
                {-U1[3].i, U1[3].r}, {U1[2].i, -U1[2].r}};
    Cf Yt[4]; mm2(Ty, Ud, Yt);
    float2* P = Pl + q*12;
    P[0] = make_float2(1.f,0.f); P[1] = make_float2(0.f,0.f);
    P[2] = make_float2(0.f,0.f); P[3] = make_float2(1.f,0.f);
    #pragma unroll
    for (int e = 0; e < 4; ++e) P[4+e] = make_float2(Zt[e].r, Zt[e].i);
    #pragma unroll
    for (int e = 0; e < 4; ++e) P[8+e] = make_float2(-Yt[e].r, -Yt[e].i);
  } else if (tid >= 8 && tid < 13) {
    int q = tid - 8;
    Cf U2[4]; fusedU(params + 37 + 3*q, U2);
    #pragma unroll
    for (int e = 0; e < 4; ++e) U2l[q*4+e] = make_float2(U2[e].r, U2[e].i);
  } else if (tid >= 16 && tid < 24) {
    int i = tid - 16;
    float th = (i < 4) ? params[15 + i] : params[52 + (i - 4)];
    crxcl[i] = cosf(0.5f*th); crxsl[i] = sinf(0.5f*th);
  } else if (tid >= 24 && tid < 30) {
    int k = tid - 24;
    Cf Ua[4], Ub[4], W[4];
    fusedU(params + 19 + 3*k, Ua);
    fusedU(params + 56 + 3*k, Ub);
    mm2(Ub, Ua, W);
    #pragma unroll
    for (int e = 0; e < 4; ++e) { Wl[k*8+2*e] = W[e].r; Wl[k*8+2*e+1] = W[e].i; }
  }
  __syncthreads();

  // ================= V build: DPP gate application, zero barriers ==========
  // thread = (col = tid>>3, quad = tid&7); row = (quad<<2)|r.
  // row bits: b4=quad>>2 (lane xor4), b3=(quad>>1)&1 (xor2), b2=quad&1 (xor1),
  //           b1 = reg bit1, b0 = reg bit0.  qubit q <-> bit 4-q.
  {
    const int quad = tid & 7, col = tid >> 3;
    const int vb2 = quad & 1, vb3 = (quad >> 1) & 1, vb4 = quad >> 2;
    Cf A[4];
    #pragma unroll
    for (int r = 0; r < 4; ++r)
      A[r] = { ((quad<<2)|r) == col ? 1.f : 0.f, 0.f };
    Cf U2g[5][4];
    #pragma unroll
    for (int q = 0; q < 5; ++q)
      #pragma unroll
      for (int e = 0; e < 4; ++e)
        U2g[q][e] = { U2l[q*4+e].x, U2l[q*4+e].y };
    float c_[8], s_[8];
    #pragma unroll
    for (int g = 0; g < 8; ++g) { c_[g] = crxcl[g]; s_[g] = crxsl[g]; }
    // L1 CRX chain: g: ctrl bit 4-g, tgt bit 3-g
    lane_crx<2>(A, c_[0], s_[0], vb4);
    lane_crx<1>(A, c_[1], s_[1], vb3);
    reg_crx_b1 (A, c_[2], s_[2], vb2);
    reg_crx_b0c1(A, c_[3], s_[3]);
    // L2 1q gates (qubit q on bit 4-q)
    lane_u<4>(A, U2g[0], vb4);
    lane_u<2>(A, U2g[1], vb3);
    lane_u<1>(A, U2g[2], vb2);
    reg_u_b1 (A, U2g[3]);
    reg_u_b0 (A, U2g[4]);
    // L2 CRX chain
    lane_crx<2>(A, c_[4], s_[4], vb4);
    lane_crx<1>(A, c_[5], s_[5], vb3);
    reg_crx_b1 (A, c_[6], s_[6], vb2);
    reg_crx_b0c1(A, c_[7], s_[7]);
    #pragma unroll
    for (int r = 0; r < 4; ++r)
      Vp[((quad<<2)|r)*32 + col] = make_float2(A[r].r, A[r].i);
  }
  __syncthreads();

  // ======== Phase C + stage 1: G-tile in regs -> contract q4 -> A1 =========
  // G_m[2jt+a][2kt+b] = sum_i s_m(i) conj(V[i][2jt+a]) V[i][2kt+b]
  //                   = (T - 2*B_m)[a][b];  B_m sums i with bit(4-m) set.
  {
    const int jt = tid >> 4, kt = tid & 15;
    float2 T[2][2], Bm[5][2][2];
    #pragma unroll
    for (int a = 0; a < 2; ++a)
      #pragma unroll
      for (int c2 = 0; c2 < 2; ++c2) {
        T[a][c2] = make_float2(0.f, 0.f);
        #pragma unroll
        for (int m = 0; m < 5; ++m) Bm[m][a][c2] = make_float2(0.f, 0.f);
      }
    #pragma unroll
    for (int i = 0; i < 32; ++i) {
      float4 vj = Vp4[i*16 + jt], vk = Vp4[i*16 + kt];
      float2 vj0{vj.x,vj.y}, vj1{vj.z,vj.w}, vk0{vk.x,vk.y}, vk1{vk.z,vk.w};
      float2 p[2][2] = {{conjmul(vj0,vk0), conjmul(vj0,vk1)},
                        {conjmul(vj1,vk0), conjmul(vj1,vk1)}};
      #pragma unroll
      for (int a = 0; a < 2; ++a)
        #pragma unroll
        for (int c2 = 0; c2 < 2; ++c2) {
          T[a][c2].x += p[a][c2].x; T[a][c2].y += p[a][c2].y;
        }
      #pragma unroll
      for (int m = 0; m < 5; ++m)
        if (i & (16 >> m)) {
          #pragma unroll
          for (int a = 0; a < 2; ++a)
            #pragma unroll
            for (int c2 = 0; c2 < 2; ++c2) {
              Bm[m][a][c2].x += p[a][c2].x; Bm[m][a][c2].y += p[a][c2].y;
            }
        }
    }
    float2 P4[12];
    #pragma unroll
    for (int e = 0; e < 12; ++e) P4[e] = Pl[4*12 + e];
    #pragma unroll
    for (int m = 0; m < 5; ++m) {
      float2 G[2][2];
      #pragma unroll
      for (int a = 0; a < 2; ++a)
        #pragma unroll
        for (int c2 = 0; c2 < 2; ++c2)
          G[a][c2] = make_float2(T[a][c2].x - 2.f*Bm[m][a][c2].x,
                                 T[a][c2].y - 2.f*Bm[m][a][c2].y);
      #pragma unroll
      for (int s = 0; s < 3; ++s) {
        float ax = 0.f, ay = 0.f;
        #pragma unroll
        for (int a = 0; a < 2; ++a)
          #pragma unroll
          for (int bb = 0; bb < 2; ++bb) {
            float2 g = G[a][bb];
            float2 p = P4[s*4 + bb*2 + a];
            ax += g.x*p.x - g.y*p.y;
            ay += g.x*p.y + g.y*p.x;
          }
        A1[(m*3 + s)*256 + (jt<<4) + kt] = make_float2(ax, ay);
      }
    }
  }
  __syncthreads();

  // ================= stages 2-4 (all m per pass) ===========================
  stageK<3, 8>(A1, A2, Pl + 3*12, tid);  __syncthreads();
  stageK<9, 4>(A2, A3, Pl + 2*12, tid);  __syncthreads();
  stageK<27,2>(A3, A4, Pl + 1*12, tid);  __syncthreads();
  // final: peel qubit 0, real part, fold 1/32
  for (int tau = tid; tau < 5*256; tau += BLOCK) {
    int n = tau & 255, m = tau >> 8;
    float val = 0.f;
    if (n < 243) {
      int t = n % 81, s = n / 81;
      const float2* Sb = A4 + (m*81 + t)*4;
      const float2* Pm = Pl + s*4;
      float ax = 0.f;
      #pragma unroll
      for (int a = 0; a < 2; ++a)
        #pragma unroll
        for (int bb = 0; bb < 2; ++bb) {
          float2 g = Sb[a*2 + bb];
          float2 p = Pm[bb*2 + a];
          ax += g.x*p.x - g.y*p.y;
        }
      val = ax * (1.f/32.f);
    }
    coefL[tau] = val;
  }
  __syncthreads();

  // ================= main work =============================================
  const int w = tid >> 6, lane = tid & 63;
  if (w == 0) {
    // ---- hidden recurrence: 243-monomial polynomial map, 1 wave ----
    float sA[4][5], sB[4][5], sC[4][5], cf[5][4];
    #pragma unroll
    for (int j = 0; j < 4; ++j) {
      int n = j*64 + lane;
      int nn = (n < 243) ? n : 0;
      int d0 = nn/81; int rm = nn - d0*81;
      int d1 = rm/27; rm -= d1*27;
      int d2 = rm/9;  rm -= d2*9;
      int d3 = rm/3;  int d4 = rm - d3*3;
      int dq[5] = {d0, d1, d2, d3, d4};
      #pragma unroll
      for (int q = 0; q < 5; ++q) {
        sA[j][q] = (dq[q] == 0) ? 1.f : 0.f;
        sB[j][q] = (dq[q] == 1) ? 1.f : 0.f;
        sC[j][q] = (dq[q] == 2) ? 1.f : 0.f;
      }
      #pragma unroll
      for (int m = 0; m < 5; ++m) cf[m][j] = coefL[m*256 + n];
    }
    const float* hp = hin + b*5;
    float h0 = hp[0], h1 = hp[1], h2 = hp[2], h3 = hp[3], h4 = hp[4];
    #pragma unroll 1
    for (int t = 0; t < TSTEPS; ++t) {
      float cq[5] = {__cosf(h0), __cosf(h1), __cosf(h2), __cosf(h3), __cosf(h4)};
      float sq[5] = {__sinf(h0), __sinf(h1), __sinf(h2), __sinf(h3), __sinf(h4)};
      float mono[4];
      #pragma unroll
      for (int j = 0; j < 4; ++j) {
        float f0 = fmaf(sB[j][0], cq[0], fmaf(sC[j][0], sq[0], sA[j][0]));
        float f1 = fmaf(sB[j][1], cq[1], fmaf(sC[j][1], sq[1], sA[j][1]));
        float f2 = fmaf(sB[j][2], cq[2], fmaf(sC[j][2], sq[2], sA[j][2]));
        float f3 = fmaf(sB[j][3], cq[3], fmaf(sC[j][3], sq[3], sA[j][3]));
        float f4 = fmaf(sB[j][4], cq[4], fmaf(sC[j][4], sq[4], sA[j][4]));
        mono[j] = ((f0*f1)*(f2*f3))*f4;
      }
      float hn[5];
      #pragma unroll
      for (int m = 0; m < 5; ++m) {
        float p01 = fmaf(cf[m][1], mono[1], cf[m][0]*mono[0]);
        float p23 = fmaf(cf[m][3], mono[3], cf[m][2]*mono[2]);
        hn[m] = wave_sum(p01 + p23);
      }
      h0 = hn[0]; h1 = hn[1]; h2 = hn[2]; h3 = hn[3]; h4 = hn[4];
    }
    if (lane < 5) {
      float hv = (lane==0) ? h0 : (lane==1) ? h1 : (lane==2) ? h2
               : (lane==3) ? h3 : h4;
      out[BATCH*TSTEPS*6 + b*5 + lane] = hv;
    }
  } else if (w == 1 && lane < TSTEPS) {
    // ---- visible outputs (pure function of x; W precomputed in LDS) ----
    const float* xp = x + (size_t)b*(TSTEPS*FEAT) + lane*FEAT;
    const float4* xp4 = (const float4*)xp;
    float4 vv[15];
    #pragma unroll
    for (int i2 = 0; i2 < 15; ++i2) vv[i2] = xp4[i2];
    float el[60];
    #pragma unroll
    for (int i2 = 0; i2 < 15; ++i2) {
      el[4*i2+0] = vv[i2].x; el[4*i2+1] = vv[i2].y;
      el[4*i2+2] = vv[i2].z; el[4*i2+3] = vv[i2].w;
    }
    float pooled[6];
    #pragma unroll
    for (int k = 0; k < 6; ++k) {
      float s = 0.f;
      #pragma unroll
      for (int f = 0; f < 10; ++f) s += el[k*10 + f];
      pooled[k] = s * 0.1f;
    }
    float mn = pooled[0], mx = pooled[0];
    #pragma unroll
    for (int v2 = 1; v2 < 6; ++v2) {
      mn = fminf(mn, pooled[v2]); mx = fmaxf(mx, pooled[v2]);
    }
    float* op = out + (size_t)b*(TSTEPS*6) + lane*6;
    #pragma unroll
    for (int k = 0; k < 6; ++k) {
      float W0r = Wl[k*8+0], W0i = Wl[k*8+1], W1r = Wl[k*8+2], W1i = Wl[k*8+3];
      float W2r = Wl[k*8+4], W2i = Wl[k*8+5], W3r = Wl[k*8+6], W3i = Wl[k*8+7];
      float ang = TWO_PI_F * (pooled[k] - mn) / (mx - mn + 1e-8f);
      float ch = __cosf(0.5f*ang), sh = __sinf(0.5f*ang);
      float v0r = W0r*ch + W1i*sh, v0i = W0i*ch - W1r*sh;
      float v1r = W2r*ch + W3i*sh, v1i = W2i*ch - W3r*sh;
      op[k] = (v0r*v0r + v0i*v0i) - (v1r*v1r + v1i*v1i);
    }
  }
}

extern "C" void kernel_launch(void* const* d_in, const int* in_sizes, int n_in,
                              void* d_out, int out_size, void* d_ws, size_t ws_size,
                              hipStream_t stream) {
  const float* x      = (const float*)d_in[0];
  const float* hidden = (const float*)d_in[1];
  const float* params = (const float*)d_in[2];
  float* out          = (float*)d_out;
  qrnn_kernel<<<dim3(BATCH), dim3(BLOCK), 0, stream>>>(x, hidden, params, out);
}

// Round 3
// 83.672 us; speedup vs baseline: 1.2243x; 1.0657x over previous
//
#include <hip/hip_runtime.h>
#include <math.h>

#define TSTEPS 48
#define FEAT 60
#define BATCH 128
#define BLOCK 256
#define TWO_PI_F 6.2831853071795864769f

// R13: loop issue-count reduction. Same math as R12 (coef[m][243] monomial
// recurrence). Changes: (1) per-lane monomial pipeline in packed f32
// (v_pk_fma_f32 / v_pk_mul_f32, 2 monomials per instr), (2) row_ror-based
// wave reduction (single DPP per stage), (3) Phase A setup spread across the
// 4 waves with fast trig (was: divergent serialized libm cosf in one wave).

struct Cf { float r, i; };
__device__ __forceinline__ Cf cmul(Cf a, Cf b){ return {a.r*b.r - a.i*b.i, a.r*b.i + a.i*b.r}; }
__device__ __forceinline__ Cf cadd(Cf a, Cf b){ return {a.r+b.r, a.i+b.i}; }
__device__ __forceinline__ void mm2(const Cf A[4], const Cf B[4], Cf D[4]) {
  D[0] = cadd(cmul(A[0],B[0]), cmul(A[1],B[2]));
  D[1] = cadd(cmul(A[0],B[1]), cmul(A[1],B[3]));
  D[2] = cadd(cmul(A[2],B[0]), cmul(A[3],B[2]));
  D[3] = cadd(cmul(A[2],B[1]), cmul(A[3],B[3]));
}

// fused U = RZ * RY * RX from 3 consecutive params (args in [0,2pi) -> fast trig ok)
__device__ __forceinline__ void fusedU(const float* p, Cf U[4]) {
  float cx = __cosf(0.5f*p[0]), sxn = __sinf(0.5f*p[0]);
  float cy = __cosf(0.5f*p[1]), syn = __sinf(0.5f*p[1]);
  float cz = __cosf(0.5f*p[2]), szn = __sinf(0.5f*p[2]);
  Cf RX[4] = {{cx,0.f},{0.f,-sxn},{0.f,-sxn},{cx,0.f}};
  Cf RY[4] = {{cy,0.f},{-syn,0.f},{syn,0.f},{cy,0.f}};
  Cf RZ[4] = {{cz,-szn},{0.f,0.f},{0.f,0.f},{cz,szn}};
  Cf M[4];
  mm2(RY, RX, M);
  mm2(RZ, M, U);
}

template<int CTRL>
__device__ __forceinline__ float dppf(float v) {
  return __int_as_float(__builtin_amdgcn_mov_dpp(__float_as_int(v), CTRL, 0xF, 0xF, true));
}

// xor-lane exchange (used by V-build gate helpers)
template<int M>
__device__ __forceinline__ float sx(float v) {
  if constexpr (M == 1)      return dppf<0xB1>(v);
  else if constexpr (M == 2) return dppf<0x4E>(v);
  else if constexpr (M == 3) return dppf<0x1B>(v);
  else if constexpr (M == 4) return dppf<0x141>(dppf<0x1B>(v));
  else                       return dppf<0x128>(v);   // M == 8 (row_ror:8)
}

template<int M>
__device__ __forceinline__ Cf sxc(Cf v){ return { sx<M>(v.r), sx<M>(v.i) }; }

// full 64-lane sum -> broadcast via readlane(63).
// ror1/2/4/8 circular reduce gives row sums in ALL row lanes; row_bcast15
// (0x142) adds row0->row1, row2->row3; row_bcast31 (0x143) adds into rows 2,3.
__device__ __forceinline__ float wave_sum(float v) {
  v += dppf<0x121>(v);   // row_ror:1
  v += dppf<0x122>(v);   // row_ror:2
  v += dppf<0x124>(v);   // row_ror:4
  v += dppf<0x128>(v);   // row_ror:8
  v += dppf<0x142>(v);   // row_bcast15
  v += dppf<0x143>(v);   // row_bcast31
  return __int_as_float(__builtin_amdgcn_readlane(__float_as_int(v), 63));
}

// ---- packed f32 (VOP3P) ----
typedef float v2f __attribute__((ext_vector_type(2)));
__device__ __forceinline__ v2f pk_fma(v2f a, v2f b, v2f c) {
  v2f d;
  asm("v_pk_fma_f32 %0, %1, %2, %3" : "=v"(d) : "v"(a), "v"(b), "v"(c));
  return d;
}
__device__ __forceinline__ v2f pk_mul(v2f a, v2f b) {
  v2f d;
  asm("v_pk_mul_f32 %0, %1, %2" : "=v"(d) : "v"(a), "v"(b));
  return d;
}

__device__ __forceinline__ float2 conjmul(float2 a, float2 b) {
  return make_float2(a.x*b.x + a.y*b.y, a.x*b.y - a.y*b.x);   // conj(a)*b
}

// ---- V-build gate helpers (4 amps/thread) ----
template<int M>
__device__ __forceinline__ void lane_u(Cf A[4], const Cf U[4], int hi) {
  Cf ca = hi ? U[3] : U[0];
  Cf cb = hi ? U[2] : U[1];
  #pragma unroll
  for (int r = 0; r < 4; ++r) {
    Cf o = sxc<M>(A[r]);
    A[r] = cadd(cmul(ca, A[r]), cmul(cb, o));
  }
}
template<int M>
__device__ __forceinline__ void lane_crx(Cf A[4], float c, float s, int cv) {
  float cc = cv ? c : 1.f, ss = cv ? s : 0.f;
  #pragma unroll
  for (int r = 0; r < 4; ++r) {
    Cf o = sxc<M>(A[r]);
    A[r] = { cc*A[r].r + ss*o.i, cc*A[r].i - ss*o.r };
  }
}
__device__ __forceinline__ void reg_u_b1(Cf A[4], const Cf U[4]) {
  #pragma unroll
  for (int k = 0; k < 2; ++k) {
    Cf a0 = A[k], a1 = A[k+2];
    A[k]   = cadd(cmul(U[0], a0), cmul(U[1], a1));
    A[k+2] = cadd(cmul(U[2], a0), cmul(U[3], a1));
  }
}
__device__ __forceinline__ void reg_u_b0(Cf A[4], const Cf U[4]) {
  #pragma unroll
  for (int k = 0; k < 4; k += 2) {
    Cf a0 = A[k], a1 = A[k+1];
    A[k]   = cadd(cmul(U[0], a0), cmul(U[1], a1));
    A[k+1] = cadd(cmul(U[2], a0), cmul(U[3], a1));
  }
}
__device__ __forceinline__ void reg_crx_b1(Cf A[4], float c, float s, int cv) {
  float cc = cv ? c : 1.f, ss = cv ? s : 0.f;
  #pragma unroll
  for (int k = 0; k < 2; ++k) {
    Cf a0 = A[k], a1 = A[k+2];
    A[k]   = { cc*a0.r + ss*a1.i, cc*a0.i - ss*a1.r };
    A[k+2] = { ss*a0.i + cc*a1.r, -ss*a0.r + cc*a1.i };
  }
}
__device__ __forceinline__ void reg_crx_b0c1(Cf A[4], float c, float s) {
  Cf a0 = A[2], a1 = A[3];
  A[2] = { c*a0.r + s*a1.i, c*a0.i - s*a1.r };
  A[3] = { s*a0.i + c*a1.r, -s*a0.r + c*a1.i };
}

// generic contraction stage over ALL m: peels current LSB qubit with P.
template<int NTs, int D>
__device__ __forceinline__ void stageK(const float2* __restrict__ src,
                                       float2* __restrict__ dst,
                                       const float2* __restrict__ Pq, int tid) {
  const int total = 5*3*NTs*D*D;
  for (int tau = tid; tau < total; tau += BLOCK) {
    int K = tau % D;
    int J = (tau / D) % D;
    int rest = tau / (D*D);
    int t = rest % NTs;
    int s = (rest / NTs) % 3;
    int m = rest / (3*NTs);
    const float2* Sb = src + (m*NTs + t)*(4*D*D);
    const float2* Pm = Pq + s*4;
    float ax = 0.f, ay = 0.f;
    #pragma unroll
    for (int a = 0; a < 2; ++a)
      #pragma unroll
      for (int bb = 0; bb < 2; ++bb) {
        float2 g = Sb[(2*J+a)*(2*D) + (2*K+bb)];
        float2 p = Pm[bb*2 + a];
        ax += g.x*p.x - g.y*p.y;
        ay += g.x*p.y + g.y*p.x;
      }
    dst[tau] = make_float2(ax, ay);
  }
}

__global__ __launch_bounds__(BLOCK)
void qrnn_kernel(const float* __restrict__ x, const float* __restrict__ hin,
                 const float* __restrict__ params, float* __restrict__ out) {
  __shared__ __align__(16) char bufA[30720];
  __shared__ __align__(16) char bufB[23040];
  __shared__ float coefL[5*256];
  __shared__ float2 Pl[5*12];
  __shared__ float2 U2l[5*4];
  __shared__ float crxcl[8], crxsl[8];
  __shared__ float Wl[6*8];

  const int b   = blockIdx.x;
  const int tid = threadIdx.x;

  float2* Vp  = (float2*)bufB;
  float4* Vp4 = (float4*)bufB;
  float2* A1  = (float2*)bufA;
  float2* A2  = (float2*)bufB;
  float2* A3  = (float2*)bufA;
  float2* A4  = (float2*)bufB;

  // ======= Phase A: small fixed tables — one task group per WAVE ==========
  if (tid < 5) {                                  // wave 0
    int q = tid;
    Cf U1[4]; fusedU(params + 3*q, U1);
    Cf T[4] = {U1[0], {-U1[1].r,-U1[1].i}, U1[2], {-U1[3].r,-U1[3].i}};
    Cf Ud[4] = {{U1[0].r,-U1[0].i},{U1[2].r,-U1[2].i},
                {U1[1].r,-U1[1].i},{U1[3].r,-U1[3].i}};
    Cf Zt[4]; mm2(T, Ud, Zt);
    Cf Ty[4] = {{-U1[1].i, U1[1].r}, {U1[0].i, -U1[0].r},
                {-U1[3].i, U1[3].r}, {U1[2].i, -U1[2].r}};
    Cf Yt[4]; mm2(Ty, Ud, Yt);
    float2* P = Pl + q*12;
    P[0] = make_float2(1.f,0.f); P[1] = make_float2(0.f,0.f);
    P[2] = make_float2(0.f,0.f); P[3] = make_float2(1.f,0.f);
    #pragma unroll
    for (int e = 0; e < 4; ++e) P[4+e] = make_float2(Zt[e].r, Zt[e].i);
    #pragma unroll
    for (int e = 0; e < 4; ++e) P[8+e] = make_float2(-Yt[e].r, -Yt[e].i);
  } else if (tid >= 64 && tid < 69) {             // wave 1
    int q = tid - 64;
    Cf U2[4]; fusedU(params + 37 + 3*q, U2);
    #pragma unroll
    for (int e = 0; e < 4; ++e) U2l[q*4+e] = make_float2(U2[e].r, U2[e].i);
  } else if (tid >= 128 && tid < 136) {           // wave 2
    int i = tid - 128;
    float th = (i < 4) ? params[15 + i] : params[52 + (i - 4)];
    crxcl[i] = __cosf(0.5f*th); crxsl[i] = __sinf(0.5f*th);
  } else if (tid >= 192 && tid < 198) {           // wave 3
    int k = tid - 192;
    Cf Ua[4], Ub[4], W[4];
    fusedU(params + 19 + 3*k, Ua);
    fusedU(params + 56 + 3*k, Ub);
    mm2(Ub, Ua, W);
    #pragma unroll
    for (int e = 0; e < 4; ++e) { Wl[k*8+2*e] = W[e].r; Wl[k*8+2*e+1] = W[e].i; }
  }
  __syncthreads();

  // ================= V build: DPP gate application, zero barriers ==========
  {
    const int quad = tid & 7, col = tid >> 3;
    const int vb2 = quad & 1, vb3 = (quad >> 1) & 1, vb4 = quad >> 2;
    Cf A[4];
    #pragma unroll
    for (int r = 0; r < 4; ++r)
      A[r] = { ((quad<<2)|r) == col ? 1.f : 0.f, 0.f };
    Cf U2g[5][4];
    #pragma unroll
    for (int q = 0; q < 5; ++q)
      #pragma unroll
      for (int e = 0; e < 4; ++e)
        U2g[q][e] = { U2l[q*4+e].x, U2l[q*4+e].y };
    float c_[8], s_[8];
    #pragma unroll
    for (int g = 0; g < 8; ++g) { c_[g] = crxcl[g]; s_[g] = crxsl[g]; }
    lane_crx<2>(A, c_[0], s_[0], vb4);
    lane_crx<1>(A, c_[1], s_[1], vb3);
    reg_crx_b1 (A, c_[2], s_[2], vb2);
    reg_crx_b0c1(A, c_[3], s_[3]);
    lane_u<4>(A, U2g[0], vb4);
    lane_u<2>(A, U2g[1], vb3);
    lane_u<1>(A, U2g[2], vb2);
    reg_u_b1 (A, U2g[3]);
    reg_u_b0 (A, U2g[4]);
    lane_crx<2>(A, c_[4], s_[4], vb4);
    lane_crx<1>(A, c_[5], s_[5], vb3);
    reg_crx_b1 (A, c_[6], s_[6], vb2);
    reg_crx_b0c1(A, c_[7], s_[7]);
    #pragma unroll
    for (int r = 0; r < 4; ++r)
      Vp[((quad<<2)|r)*32 + col] = make_float2(A[r].r, A[r].i);
  }
  __syncthreads();

  // ======== Phase C + stage 1: G-tile in regs -> contract q4 -> A1 =========
  {
    const int jt = tid >> 4, kt = tid & 15;
    float2 T[2][2], Bm[5][2][2];
    #pragma unroll
    for (int a = 0; a < 2; ++a)
      #pragma unroll
      for (int c2 = 0; c2 < 2; ++c2) {
        T[a][c2] = make_float2(0.f, 0.f);
        #pragma unroll
        for (int m = 0; m < 5; ++m) Bm[m][a][c2] = make_float2(0.f, 0.f);
      }
    #pragma unroll
    for (int i = 0; i < 32; ++i) {
      float4 vj = Vp4[i*16 + jt], vk = Vp4[i*16 + kt];
      float2 vj0{vj.x,vj.y}, vj1{vj.z,vj.w}, vk0{vk.x,vk.y}, vk1{vk.z,vk.w};
      float2 p[2][2] = {{conjmul(vj0,vk0), conjmul(vj0,vk1)},
                        {conjmul(vj1,vk0), conjmul(vj1,vk1)}};
      #pragma unroll
      for (int a = 0; a < 2; ++a)
        #pragma unroll
        for (int c2 = 0; c2 < 2; ++c2) {
          T[a][c2].x += p[a][c2].x; T[a][c2].y += p[a][c2].y;
        }
      #pragma unroll
      for (int m = 0; m < 5; ++m)
        if (i & (16 >> m)) {
          #pragma unroll
          for (int a = 0; a < 2; ++a)
            #pragma unroll
            for (int c2 = 0; c2 < 2; ++c2) {
              Bm[m][a][c2].x += p[a][c2].x; Bm[m][a][c2].y += p[a][c2].y;
            }
        }
    }
    float2 P4[12];
    #pragma unroll
    for (int e = 0; e < 12; ++e) P4[e] = Pl[4*12 + e];
    #pragma unroll
    for (int m = 0; m < 5; ++m) {
      float2 G[2][2];
      #pragma unroll
      for (int a = 0; a < 2; ++a)
        #pragma unroll
        for (int c2 = 0; c2 < 2; ++c2)
          G[a][c2] = make_float2(T[a][c2].x - 2.f*Bm[m][a][c2].x,
                                 T[a][c2].y - 2.f*Bm[m][a][c2].y);
      #pragma unroll
      for (int s = 0; s < 3; ++s) {
        float ax = 0.f, ay = 0.f;
        #pragma unroll
        for (int a = 0; a < 2; ++a)
          #pragma unroll
          for (int bb = 0; bb < 2; ++bb) {
            float2 g = G[a][bb];
            float2 p = P4[s*4 + bb*2 + a];
            ax += g.x*p.x - g.y*p.y;
            ay += g.x*p.y + g.y*p.x;
          }
        A1[(m*3 + s)*256 + (jt<<4) + kt] = make_float2(ax, ay);
      }
    }
  }
  __syncthreads();

  stageK<3, 8>(A1, A2, Pl + 3*12, tid);  __syncthreads();
  stageK<9, 4>(A2, A3, Pl + 2*12, tid);  __syncthreads();
  stageK<27,2>(A3, A4, Pl + 1*12, tid);  __syncthreads();
  for (int tau = tid; tau < 5*256; tau += BLOCK) {
    int n = tau & 255, m = tau >> 8;
    float val = 0.f;
    if (n < 243) {
      int t = n % 81, s = n / 81;
      const float2* Sb = A4 + (m*81 + t)*4;
      const float2* Pm = Pl + s*4;
      float ax = 0.f;
      #pragma unroll
      for (int a = 0; a < 2; ++a)
        #pragma unroll
        for (int bb = 0; bb < 2; ++bb) {
          float2 g = Sb[a*2 + bb];
          float2 p = Pm[bb*2 + a];
          ax += g.x*p.x - g.y*p.y;
        }
      val = ax * (1.f/32.f);
    }
    coefL[tau] = val;
  }
  __syncthreads();

  // ================= main work =============================================
  const int w = tid >> 6, lane = tid & 63;
  if (w == 0) {
    // ---- hidden recurrence: 243-monomial map, packed-f32 pipeline ----
    // pairset s covers monomials n = lane + (2s)*64 and n = lane + (2s+1)*64
    v2f sAp[2][5], sBp[2][5], sCp[2][5], cfp[5][2];
    #pragma unroll
    for (int s = 0; s < 2; ++s) {
      #pragma unroll
      for (int half = 0; half < 2; ++half) {
        int n = (2*s + half)*64 + lane;
        int nn = (n < 243) ? n : 0;
        int d0 = nn/81; int rm = nn - d0*81;
        int d1 = rm/27; rm -= d1*27;
        int d2 = rm/9;  rm -= d2*9;
        int d3 = rm/3;  int d4 = rm - d3*3;
        int dq[5] = {d0, d1, d2, d3, d4};
        #pragma unroll
        for (int q = 0; q < 5; ++q) {
          if (half == 0) {
            sAp[s][q].x = (dq[q] == 0) ? 1.f : 0.f;
            sBp[s][q].x = (dq[q] == 1) ? 1.f : 0.f;
            sCp[s][q].x = (dq[q] == 2) ? 1.f : 0.f;
          } else {
            sAp[s][q].y = (dq[q] == 0) ? 1.f : 0.f;
            sBp[s][q].y = (dq[q] == 1) ? 1.f : 0.f;
            sCp[s][q].y = (dq[q] == 2) ? 1.f : 0.f;
          }
        }
      }
    }
    #pragma unroll
    for (int m = 0; m < 5; ++m) {
      cfp[m][0].x = coefL[m*256 + lane];
      cfp[m][0].y = coefL[m*256 + lane + 64];
      cfp[m][1].x = coefL[m*256 + lane + 128];
      cfp[m][1].y = coefL[m*256 + lane + 192];
    }
    const float* hp = hin + b*5;
    float h0 = hp[0], h1 = hp[1], h2 = hp[2], h3 = hp[3], h4 = hp[4];
    #pragma unroll 1
    for (int t = 0; t < TSTEPS; ++t) {
      float cq[5] = {__cosf(h0), __cosf(h1), __cosf(h2), __cosf(h3), __cosf(h4)};
      float sq[5] = {__sinf(h0), __sinf(h1), __sinf(h2), __sinf(h3), __sinf(h4)};
      v2f cqp[5], sqp[5];
      #pragma unroll
      for (int q = 0; q < 5; ++q) {
        cqp[q] = (v2f){cq[q], cq[q]};
        sqp[q] = (v2f){sq[q], sq[q]};
      }
      v2f monoP[2];
      #pragma unroll
      for (int s = 0; s < 2; ++s) {
        v2f f0 = pk_fma(sBp[s][0], cqp[0], pk_fma(sCp[s][0], sqp[0], sAp[s][0]));
        v2f f1 = pk_fma(sBp[s][1], cqp[1], pk_fma(sCp[s][1], sqp[1], sAp[s][1]));
        v2f f2 = pk_fma(sBp[s][2], cqp[2], pk_fma(sCp[s][2], sqp[2], sAp[s][2]));
        v2f f3 = pk_fma(sBp[s][3], cqp[3], pk_fma(sCp[s][3], sqp[3], sAp[s][3]));
        v2f f4 = pk_fma(sBp[s][4], cqp[4], pk_fma(sCp[s][4], sqp[4], sAp[s][4]));
        monoP[s] = pk_mul(pk_mul(pk_mul(f0, f1), pk_mul(f2, f3)), f4);
      }
      float hn[5];
      #pragma unroll
      for (int m = 0; m < 5; ++m) {
        v2f tacc = pk_mul(monoP[0], cfp[m][0]);
        tacc = pk_fma(monoP[1], cfp[m][1], tacc);
        hn[m] = wave_sum(tacc.x + tacc.y);
      }
      h0 = hn[0]; h1 = hn[1]; h2 = hn[2]; h3 = hn[3]; h4 = hn[4];
    }
    if (lane < 5) {
      float hv = (lane==0) ? h0 : (lane==1) ? h1 : (lane==2) ? h2
               : (lane==3) ? h3 : h4;
      out[BATCH*TSTEPS*6 + b*5 + lane] = hv;
    }
  } else if (w == 1 && lane < TSTEPS) {
    // ---- visible outputs (pure function of x; W precomputed in LDS) ----
    const float* xp = x + (size_t)b*(TSTEPS*FEAT) + lane*FEAT;
    const float4* xp4 = (const float4*)xp;
    float4 vv[15];
    #pragma unroll
    for (int i2 = 0; i2 < 15; ++i2) vv[i2] = xp4[i2];
    float el[60];
    #pragma unroll
    for (int i2 = 0; i2 < 15; ++i2) {
      el[4*i2+0] = vv[i2].x; el[4*i2+1] = vv[i2].y;
      el[4*i2+2] = vv[i2].z; el[4*i2+3] = vv[i2].w;
    }
    float pooled[6];
    #pragma unroll
    for (int k = 0; k < 6; ++k) {
      float s = 0.f;
      #pragma unroll
      for (int f = 0; f < 10; ++f) s += el[k*10 + f];
      pooled[k] = s * 0.1f;
    }
    float mn = pooled[0], mx = pooled[0];
    #pragma unroll
    for (int v2 = 1; v2 < 6; ++v2) {
      mn = fminf(mn, pooled[v2]); mx = fmaxf(mx, pooled[v2]);
    }
    float* op = out + (size_t)b*(TSTEPS*6) + lane*6;
    #pragma unroll
    for (int k = 0; k < 6; ++k) {
      float W0r = Wl[k*8+0], W0i = Wl[k*8+1], W1r = Wl[k*8+2], W1i = Wl[k*8+3];
      float W2r = Wl[k*8+4], W2i = Wl[k*8+5], W3r = Wl[k*8+6], W3i = Wl[k*8+7];
      float ang = TWO_PI_F * (pooled[k] - mn) / (mx - mn + 1e-8f);
      float ch = __cosf(0.5f*ang), sh = __sinf(0.5f*ang);
      float v0r = W0r*ch + W1i*sh, v0i = W0i*ch - W1r*sh;
      float v1r = W2r*ch + W3i*sh, v1i = W2i*ch - W3r*sh;
      op[k] = (v0r*v0r + v0i*v0i) - (v1r*v1r + v1i*v1i);
    }
  }
}

extern "C" void kernel_launch(void* const* d_in, const int* in_sizes, int n_in,
                              void* d_out, int out_size, void* d_ws, size_t ws_size,
                              hipStream_t stream) {
  const float* x      = (const float*)d_in[0];
  const float* hidden = (const float*)d_in[1];
  const float* params = (const float*)d_in[2];
  float* out          = (float*)d_out;
  qrnn_kernel<<<dim3(BATCH), dim3(BLOCK), 0, stream>>>(x, hidden, params, out);
}

// Round 4
// 82.431 us; speedup vs baseline: 1.2427x; 1.0151x over previous
//
#include <hip/hip_runtime.h>
#include <math.h>

#define TSTEPS 48
#define FEAT 60
#define BATCH 128
#define BLOCK 512
#define TWO_PI_F 6.2831853071795864769f
#define INV2PI_F 0.15915494309189535f

// R14: critical-wave instruction cut.  Same math as R13 (coef[m][243]
// monomial recurrence).  Changes:
//  (1) BLOCK 512: Phase C i-loop split across thread-halves; the P4
//      contraction is linear in G, so each half contracts its own partial
//      G = T_g - 2*B_g and halves are summed in A1 (B writes, A adds).
//      m=0 freebie: bit4 constant per half -> G0 = +T (half0) / -T (half1).
//  (2) coef pre-scaled by 1/(2pi); h kept in REVOLUTIONS; raw v_sin/v_cos
//      via __builtin_amdgcn_sinf/cosf (no per-step 1/2pi multiplies).

struct Cf { float r, i; };
__device__ __forceinline__ Cf cmul(Cf a, Cf b){ return {a.r*b.r - a.i*b.i, a.r*b.i + a.i*b.r}; }
__device__ __forceinline__ Cf cadd(Cf a, Cf b){ return {a.r+b.r, a.i+b.i}; }
__device__ __forceinline__ void mm2(const Cf A[4], const Cf B[4], Cf D[4]) {
  D[0] = cadd(cmul(A[0],B[0]), cmul(A[1],B[2]));
  D[1] = cadd(cmul(A[0],B[1]), cmul(A[1],B[3]));
  D[2] = cadd(cmul(A[2],B[0]), cmul(A[3],B[2]));
  D[3] = cadd(cmul(A[2],B[1]), cmul(A[3],B[3]));
}

// fused U = RZ * RY * RX from 3 consecutive params (args in [0,2pi))
__device__ __forceinline__ void fusedU(const float* p, Cf U[4]) {
  float cx = __cosf(0.5f*p[0]), sxn = __sinf(0.5f*p[0]);
  float cy = __cosf(0.5f*p[1]), syn = __sinf(0.5f*p[1]);
  float cz = __cosf(0.5f*p[2]), szn = __sinf(0.5f*p[2]);
  Cf RX[4] = {{cx,0.f},{0.f,-sxn},{0.f,-sxn},{cx,0.f}};
  Cf RY[4] = {{cy,0.f},{-syn,0.f},{syn,0.f},{cy,0.f}};
  Cf RZ[4] = {{cz,-szn},{0.f,0.f},{0.f,0.f},{cz,szn}};
  Cf M[4];
  mm2(RY, RX, M);
  mm2(RZ, M, U);
}

template<int CTRL>
__device__ __forceinline__ float dppf(float v) {
  return __int_as_float(__builtin_amdgcn_mov_dpp(__float_as_int(v), CTRL, 0xF, 0xF, true));
}

template<int M>
__device__ __forceinline__ float sx(float v) {
  if constexpr (M == 1)      return dppf<0xB1>(v);
  else if constexpr (M == 2) return dppf<0x4E>(v);
  else if constexpr (M == 3) return dppf<0x1B>(v);
  else if constexpr (M == 4) return dppf<0x141>(dppf<0x1B>(v));
  else                       return dppf<0x128>(v);   // M == 8
}

template<int M>
__device__ __forceinline__ Cf sxc(Cf v){ return { sx<M>(v.r), sx<M>(v.i) }; }

// full 64-lane sum -> broadcast via readlane(63) (verified lineage R13)
__device__ __forceinline__ float wave_sum(float v) {
  v += dppf<0x121>(v);   // row_ror:1
  v += dppf<0x122>(v);   // row_ror:2
  v += dppf<0x124>(v);   // row_ror:4
  v += dppf<0x128>(v);   // row_ror:8
  v += dppf<0x142>(v);   // row_bcast15
  v += dppf<0x143>(v);   // row_bcast31
  return __int_as_float(__builtin_amdgcn_readlane(__float_as_int(v), 63));
}

// ---- packed f32 (VOP3P) ----
typedef float v2f __attribute__((ext_vector_type(2)));
__device__ __forceinline__ v2f pk_fma(v2f a, v2f b, v2f c) {
  v2f d;
  asm("v_pk_fma_f32 %0, %1, %2, %3" : "=v"(d) : "v"(a), "v"(b), "v"(c));
  return d;
}
__device__ __forceinline__ v2f pk_mul(v2f a, v2f b) {
  v2f d;
  asm("v_pk_mul_f32 %0, %1, %2" : "=v"(d) : "v"(a), "v"(b));
  return d;
}

__device__ __forceinline__ float2 conjmul(float2 a, float2 b) {
  return make_float2(a.x*b.x + a.y*b.y, a.x*b.y - a.y*b.x);   // conj(a)*b
}

// ---- V-build gate helpers (4 amps/thread) ----
template<int M>
__device__ __forceinline__ void lane_u(Cf A[4], const Cf U[4], int hi) {
  Cf ca = hi ? U[3] : U[0];
  Cf cb = hi ? U[2] : U[1];
  #pragma unroll
  for (int r = 0; r < 4; ++r) {
    Cf o = sxc<M>(A[r]);
    A[r] = cadd(cmul(ca, A[r]), cmul(cb, o));
  }
}
template<int M>
__device__ __forceinline__ void lane_crx(Cf A[4], float c, float s, int cv) {
  float cc = cv ? c : 1.f, ss = cv ? s : 0.f;
  #pragma unroll
  for (int r = 0; r < 4; ++r) {
    Cf o = sxc<M>(A[r]);
    A[r] = { cc*A[r].r + ss*o.i, cc*A[r].i - ss*o.r };
  }
}
__device__ __forceinline__ void reg_u_b1(Cf A[4], const Cf U[4]) {
  #pragma unroll
  for (int k = 0; k < 2; ++k) {
    Cf a0 = A[k], a1 = A[k+2];
    A[k]   = cadd(cmul(U[0], a0), cmul(U[1], a1));
    A[k+2] = cadd(cmul(U[2], a0), cmul(U[3], a1));
  }
}
__device__ __forceinline__ void reg_u_b0(Cf A[4], const Cf U[4]) {
  #pragma unroll
  for (int k = 0; k < 4; k += 2) {
    Cf a0 = A[k], a1 = A[k+1];
    A[k]   = cadd(cmul(U[0], a0), cmul(U[1], a1));
    A[k+1] = cadd(cmul(U[2], a0), cmul(U[3], a1));
  }
}
__device__ __forceinline__ void reg_crx_b1(Cf A[4], float c, float s, int cv) {
  float cc = cv ? c : 1.f, ss = cv ? s : 0.f;
  #pragma unroll
  for (int k = 0; k < 2; ++k) {
    Cf a0 = A[k], a1 = A[k+2];
    A[k]   = { cc*a0.r + ss*a1.i, cc*a0.i - ss*a1.r };
    A[k+2] = { ss*a0.i + cc*a1.r, -ss*a0.r + cc*a1.i };
  }
}
__device__ __forceinline__ void reg_crx_b0c1(Cf A[4], float c, float s) {
  Cf a0 = A[2], a1 = A[3];
  A[2] = { c*a0.r + s*a1.i, c*a0.i - s*a1.r };
  A[3] = { s*a0.i + c*a1.r, -s*a0.r + c*a1.i };
}

// generic contraction stage over ALL m: peels current LSB qubit with P.
template<int NTs, int D>
__device__ __forceinline__ void stageK(const float2* __restrict__ src,
                                       float2* __restrict__ dst,
                                       const float2* __restrict__ Pq, int tid) {
  const int total = 5*3*NTs*D*D;
  for (int tau = tid; tau < total; tau += BLOCK) {
    int K = tau % D;
    int J = (tau / D) % D;
    int rest = tau / (D*D);
    int t = rest % NTs;
    int s = (rest / NTs) % 3;
    int m = rest / (3*NTs);
    const float2* Sb = src + (m*NTs + t)*(4*D*D);
    const float2* Pm = Pq + s*4;
    float ax = 0.f, ay = 0.f;
    #pragma unroll
    for (int a = 0; a < 2; ++a)
      #pragma unroll
      for (int bb = 0; bb < 2; ++bb) {
        float2 g = Sb[(2*J+a)*(2*D) + (2*K+bb)];
        float2 p = Pm[bb*2 + a];
        ax += g.x*p.x - g.y*p.y;
        ay += g.x*p.y + g.y*p.x;
      }
    dst[tau] = make_float2(ax, ay);
  }
}

__global__ __launch_bounds__(BLOCK)
void qrnn_kernel(const float* __restrict__ x, const float* __restrict__ hin,
                 const float* __restrict__ params, float* __restrict__ out) {
  __shared__ __align__(16) char bufA[30720];
  __shared__ __align__(16) char bufB[23040];
  __shared__ float coefL[5*256];
  __shared__ float2 Pl[5*12];
  __shared__ float2 U2l[5*4];
  __shared__ float crxcl[8], crxsl[8];
  __shared__ float Wl[6*8];

  const int b   = blockIdx.x;
  const int tid = threadIdx.x;

  float2* Vp  = (float2*)bufB;
  float4* Vp4 = (float4*)bufB;
  float2* A1  = (float2*)bufA;
  float2* A2  = (float2*)bufB;
  float2* A3  = (float2*)bufA;
  float2* A4  = (float2*)bufB;

  // ======= Phase A: small fixed tables — one task group per wave ==========
  if (tid < 5) {                                  // wave 0
    int q = tid;
    Cf U1[4]; fusedU(params + 3*q, U1);
    Cf T[4] = {U1[0], {-U1[1].r,-U1[1].i}, U1[2], {-U1[3].r,-U1[3].i}};
    Cf Ud[4] = {{U1[0].r,-U1[0].i},{U1[2].r,-U1[2].i},
                {U1[1].r,-U1[1].i},{U1[3].r,-U1[3].i}};
    Cf Zt[4]; mm2(T, Ud, Zt);
    Cf Ty[4] = {{-U1[1].i, U1[1].r}, {U1[0].i, -U1[0].r},
                {-U1[3].i, U1[3].r}, {U1[2].i, -U1[2].r}};
    Cf Yt[4]; mm2(Ty, Ud, Yt);
    float2* P = Pl + q*12;
    P[0] = make_float2(1.f,0.f); P[1] = make_float2(0.f,0.f);
    P[2] = make_float2(0.f,0.f); P[3] = make_float2(1.f,0.f);
    #pragma unroll
    for (int e = 0; e < 4; ++e) P[4+e] = make_float2(Zt[e].r, Zt[e].i);
    #pragma unroll
    for (int e = 0; e < 4; ++e) P[8+e] = make_float2(-Yt[e].r, -Yt[e].i);
  } else if (tid >= 64 && tid < 69) {             // wave 1
    int q = tid - 64;
    Cf U2[4]; fusedU(params + 37 + 3*q, U2);
    #pragma unroll
    for (int e = 0; e < 4; ++e) U2l[q*4+e] = make_float2(U2[e].r, U2[e].i);
  } else if (tid >= 128 && tid < 136) {           // wave 2
    int i = tid - 128;
    float th = (i < 4) ? params[15 + i] : params[52 + (i - 4)];
    crxcl[i] = __cosf(0.5f*th); crxsl[i] = __sinf(0.5f*th);
  } else if (tid >= 192 && tid < 198) {           // wave 3
    int k = tid - 192;
    Cf Ua[4], Ub[4], W[4];
    fusedU(params + 19 + 3*k, Ua);
    fusedU(params + 56 + 3*k, Ub);
    mm2(Ub, Ua, W);
    #pragma unroll
    for (int e = 0; e < 4; ++e) { Wl[k*8+2*e] = W[e].r; Wl[k*8+2*e+1] = W[e].i; }
  }
  __syncthreads();

  // ============ V build: DPP gate application (threads 0..255) ============
  if (tid < 256) {
    const int quad = tid & 7, col = tid >> 3;
    const int vb2 = quad & 1, vb3 = (quad >> 1) & 1, vb4 = quad >> 2;
    Cf A[4];
    #pragma unroll
    for (int r = 0; r < 4; ++r)
      A[r] = { ((quad<<2)|r) == col ? 1.f : 0.f, 0.f };
    Cf U2g[5][4];
    #pragma unroll
    for (int q = 0; q < 5; ++q)
      #pragma unroll
      for (int e = 0; e < 4; ++e)
        U2g[q][e] = { U2l[q*4+e].x, U2l[q*4+e].y };
    float c_[8], s_[8];
    #pragma unroll
    for (int g = 0; g < 8; ++g) { c_[g] = crxcl[g]; s_[g] = crxsl[g]; }
    lane_crx<2>(A, c_[0], s_[0], vb4);
    lane_crx<1>(A, c_[1], s_[1], vb3);
    reg_crx_b1 (A, c_[2], s_[2], vb2);
    reg_crx_b0c1(A, c_[3], s_[3]);
    lane_u<4>(A, U2g[0], vb4);
    lane_u<2>(A, U2g[1], vb3);
    lane_u<1>(A, U2g[2], vb2);
    reg_u_b1 (A, U2g[3]);
    reg_u_b0 (A, U2g[4]);
    lane_crx<2>(A, c_[4], s_[4], vb4);
    lane_crx<1>(A, c_[5], s_[5], vb3);
    reg_crx_b1 (A, c_[6], s_[6], vb2);
    reg_crx_b0c1(A, c_[7], s_[7]);
    #pragma unroll
    for (int r = 0; r < 4; ++r)
      Vp[((quad<<2)|r)*32 + col] = make_float2(A[r].r, A[r].i);
  }
  __syncthreads();

  // ====== Phase C + stage 1, i-split across halves (linear in G) ==========
  // half h covers i in [16h, 16h+16); B0 freebie: G0 = +T (h=0) / -T (h=1).
  {
    const int jk = tid & 255;
    const int jt = jk >> 4, kt = jk & 15;
    const int half = tid >> 8;
    const int ibase = half << 4;
    float2 Tacc[2][2], Bacc[4][2][2];
    #pragma unroll
    for (int a = 0; a < 2; ++a)
      #pragma unroll
      for (int c2 = 0; c2 < 2; ++c2) {
        Tacc[a][c2] = make_float2(0.f, 0.f);
        #pragma unroll
        for (int mb = 0; mb < 4; ++mb) Bacc[mb][a][c2] = make_float2(0.f, 0.f);
      }
    #pragma unroll
    for (int ii = 0; ii < 16; ++ii) {
      const int i = ibase + ii;
      float4 vj = Vp4[i*16 + jt], vk = Vp4[i*16 + kt];
      float2 vj0{vj.x,vj.y}, vj1{vj.z,vj.w}, vk0{vk.x,vk.y}, vk1{vk.z,vk.w};
      float2 p[2][2] = {{conjmul(vj0,vk0), conjmul(vj0,vk1)},
                        {conjmul(vj1,vk0), conjmul(vj1,vk1)}};
      #pragma unroll
      for (int a = 0; a < 2; ++a)
        #pragma unroll
        for (int c2 = 0; c2 < 2; ++c2) {
          Tacc[a][c2].x += p[a][c2].x; Tacc[a][c2].y += p[a][c2].y;
        }
      #pragma unroll
      for (int mb = 0; mb < 4; ++mb)
        if (ii & (8 >> mb)) {
          #pragma unroll
          for (int a = 0; a < 2; ++a)
            #pragma unroll
            for (int c2 = 0; c2 < 2; ++c2) {
              Bacc[mb][a][c2].x += p[a][c2].x; Bacc[mb][a][c2].y += p[a][c2].y;
            }
        }
    }
    float2 P4[12];
    #pragma unroll
    for (int e = 0; e < 12; ++e) P4[e] = Pl[4*12 + e];
    const float sgn0 = half ? -1.f : 1.f;
    float2 acc[15];
    #pragma unroll
    for (int m = 0; m < 5; ++m) {
      float2 G[2][2];
      #pragma unroll
      for (int a = 0; a < 2; ++a)
        #pragma unroll
        for (int c2 = 0; c2 < 2; ++c2) {
          float2 t = Tacc[a][c2];
          if (m == 0) G[a][c2] = make_float2(sgn0*t.x, sgn0*t.y);
          else {
            float2 bv = Bacc[m-1][a][c2];
            G[a][c2] = make_float2(t.x - 2.f*bv.x, t.y - 2.f*bv.y);
          }
        }
      #pragma unroll
      for (int s = 0; s < 3; ++s) {
        float ax = 0.f, ay = 0.f;
        #pragma unroll
        for (int a = 0; a < 2; ++a)
          #pragma unroll
          for (int bb = 0; bb < 2; ++bb) {
            float2 g = G[a][bb];
            float2 p = P4[s*4 + bb*2 + a];
            ax += g.x*p.x - g.y*p.y;
            ay += g.x*p.y + g.y*p.x;
          }
        acc[m*3 + s] = make_float2(ax, ay);
      }
    }
    if (half) {                       // group B writes its contribution
      #pragma unroll
      for (int e = 0; e < 15; ++e) A1[e*256 + jk] = acc[e];
    }
    __syncthreads();
    if (!half) {                      // group A accumulates on top
      #pragma unroll
      for (int e = 0; e < 15; ++e) {
        float2 v = A1[e*256 + jk];
        A1[e*256 + jk] = make_float2(v.x + acc[e].x, v.y + acc[e].y);
      }
    }
  }
  __syncthreads();

  stageK<3, 8>(A1, A2, Pl + 3*12, tid);  __syncthreads();
  stageK<9, 4>(A2, A3, Pl + 2*12, tid);  __syncthreads();
  stageK<27,2>(A3, A4, Pl + 1*12, tid);  __syncthreads();
  // final: peel qubit 0, real part, fold 1/32 AND 1/(2pi)  (h in revolutions)
  for (int tau = tid; tau < 5*256; tau += BLOCK) {
    int n = tau & 255, m = tau >> 8;
    float val = 0.f;
    if (n < 243) {
      int t = n % 81, s = n / 81;
      const float2* Sb = A4 + (m*81 + t)*4;
      const float2* Pm = Pl + s*4;
      float ax = 0.f;
      #pragma unroll
      for (int a = 0; a < 2; ++a)
        #pragma unroll
        for (int bb = 0; bb < 2; ++bb) {
          float2 g = Sb[a*2 + bb];
          float2 p = Pm[bb*2 + a];
          ax += g.x*p.x - g.y*p.y;
        }
      val = ax * 4.97359197e-3f;      // 1/32 * 1/(2pi)
    }
    coefL[tau] = val;
  }
  __syncthreads();

  // ================= main work =============================================
  const int w = tid >> 6, lane = tid & 63;
  if (w == 0) {
    // ---- hidden recurrence: 243-monomial map, packed-f32, h in revs ----
    v2f sAp[2][5], sBp[2][5], sCp[2][5], cfp[5][2];
    #pragma unroll
    for (int s = 0; s < 2; ++s) {
      #pragma unroll
      for (int half = 0; half < 2; ++half) {
        int n = (2*s + half)*64 + lane;
        int nn = (n < 243) ? n : 0;
        int d0 = nn/81; int rm = nn - d0*81;
        int d1 = rm/27; rm -= d1*27;
        int d2 = rm/9;  rm -= d2*9;
        int d3 = rm/3;  int d4 = rm - d3*3;
        int dq[5] = {d0, d1, d2, d3, d4};
        #pragma unroll
        for (int q = 0; q < 5; ++q) {
          if (half == 0) {
            sAp[s][q].x = (dq[q] == 0) ? 1.f : 0.f;
            sBp[s][q].x = (dq[q] == 1) ? 1.f : 0.f;
            sCp[s][q].x = (dq[q] == 2) ? 1.f : 0.f;
          } else {
            sAp[s][q].y = (dq[q] == 0) ? 1.f : 0.f;
            sBp[s][q].y = (dq[q] == 1) ? 1.f : 0.f;
            sCp[s][q].y = (dq[q] == 2) ? 1.f : 0.f;
          }
        }
      }
    }
    #pragma unroll
    for (int m = 0; m < 5; ++m) {
      cfp[m][0].x = coefL[m*256 + lane];
      cfp[m][0].y = coefL[m*256 + lane + 64];
      cfp[m][1].x = coefL[m*256 + lane + 128];
      cfp[m][1].y = coefL[m*256 + lane + 192];
    }
    const float* hp = hin + b*5;
    float h0 = hp[0]*INV2PI_F, h1 = hp[1]*INV2PI_F, h2 = hp[2]*INV2PI_F,
          h3 = hp[3]*INV2PI_F, h4 = hp[4]*INV2PI_F;
    #pragma unroll 1
    for (int t = 0; t < TSTEPS; ++t) {
      float cq[5] = {__builtin_amdgcn_cosf(h0), __builtin_amdgcn_cosf(h1),
                     __builtin_amdgcn_cosf(h2), __builtin_amdgcn_cosf(h3),
                     __builtin_amdgcn_cosf(h4)};
      float sq[5] = {__builtin_amdgcn_sinf(h0), __builtin_amdgcn_sinf(h1),
                     __builtin_amdgcn_sinf(h2), __builtin_amdgcn_sinf(h3),
                     __builtin_amdgcn_sinf(h4)};
      v2f cqp[5], sqp[5];
      #pragma unroll
      for (int q = 0; q < 5; ++q) {
        cqp[q] = (v2f){cq[q], cq[q]};
        sqp[q] = (v2f){sq[q], sq[q]};
      }
      v2f monoP[2];
      #pragma unroll
      for (int s = 0; s < 2; ++s) {
        v2f f0 = pk_fma(sBp[s][0], cqp[0], pk_fma(sCp[s][0], sqp[0], sAp[s][0]));
        v2f f1 = pk_fma(sBp[s][1], cqp[1], pk_fma(sCp[s][1], sqp[1], sAp[s][1]));
        v2f f2 = pk_fma(sBp[s][2], cqp[2], pk_fma(sCp[s][2], sqp[2], sAp[s][2]));
        v2f f3 = pk_fma(sBp[s][3], cqp[3], pk_fma(sCp[s][3], sqp[3], sAp[s][3]));
        v2f f4 = pk_fma(sBp[s][4], cqp[4], pk_fma(sCp[s][4], sqp[4], sAp[s][4]));
        monoP[s] = pk_mul(pk_mul(pk_mul(f0, f1), pk_mul(f2, f3)), f4);
      }
      float hn[5];
      #pragma unroll
      for (int m = 0; m < 5; ++m) {
        v2f tacc = pk_mul(monoP[0], cfp[m][0]);
        tacc = pk_fma(monoP[1], cfp[m][1], tacc);
        hn[m] = wave_sum(tacc.x + tacc.y);
      }
      h0 = hn[0]; h1 = hn[1]; h2 = hn[2]; h3 = hn[3]; h4 = hn[4];
    }
    if (lane < 5) {
      float hv = (lane==0) ? h0 : (lane==1) ? h1 : (lane==2) ? h2
               : (lane==3) ? h3 : h4;
      out[BATCH*TSTEPS*6 + b*5 + lane] = TWO_PI_F*hv;   // revs -> original units
    }
  } else if (w == 1 && lane < TSTEPS) {
    // ---- visible outputs (pure function of x; W precomputed in LDS) ----
    const float* xp = x + (size_t)b*(TSTEPS*FEAT) + lane*FEAT;
    const float4* xp4 = (const float4*)xp;
    float4 vv[15];
    #pragma unroll
    for (int i2 = 0; i2 < 15; ++i2) vv[i2] = xp4[i2];
    float el[60];
    #pragma unroll
    for (int i2 = 0; i2 < 15; ++i2) {
      el[4*i2+0] = vv[i2].x; el[4*i2+1] = vv[i2].y;
      el[4*i2+2] = vv[i2].z; el[4*i2+3] = vv[i2].w;
    }
    float pooled[6];
    #pragma unroll
    for (int k = 0; k < 6; ++k) {
      float s = 0.f;
      #pragma unroll
      for (int f = 0; f < 10; ++f) s += el[k*10 + f];
      pooled[k] = s * 0.1f;
    }
    float mn = pooled[0], mx = pooled[0];
    #pragma unroll
    for (int v2 = 1; v2 < 6; ++v2) {
      mn = fminf(mn, pooled[v2]); mx = fmaxf(mx, pooled[v2]);
    }
    float* op = out + (size_t)b*(TSTEPS*6) + lane*6;
    #pragma unroll
    for (int k = 0; k < 6; ++k) {
      float W0r = Wl[k*8+0], W0i = Wl[k*8+1], W1r = Wl[k*8+2], W1i = Wl[k*8+3];
      float W2r = Wl[k*8+4], W2i = Wl[k*8+5], W3r = Wl[k*8+6], W3i = Wl[k*8+7];
      float ang = TWO_PI_F * (pooled[k] - mn) / (mx - mn + 1e-8f);
      float ch = __cosf(0.5f*ang), sh = __sinf(0.5f*ang);
      float v0r = W0r*ch + W1i*sh, v0i = W0i*ch - W1r*sh;
      float v1r = W2r*ch + W3i*sh, v1i = W2i*ch - W3r*sh;
      op[k] = (v0r*v0r + v0i*v0i) - (v1r*v1r + v1i*v1i);
    }
  }
}

extern "C" void kernel_launch(void* const* d_in, const int* in_sizes, int n_in,
                              void* d_out, int out_size, void* d_ws, size_t ws_size,
                              hipStream_t stream) {
  const float* x      = (const float*)d_in[0];
  const float* hidden = (const float*)d_in[1];
  const float* params = (const float*)d_in[2];
  float* out          = (float*)d_out;
  qrnn_kernel<<<dim3(BATCH), dim3(BLOCK), 0, stream>>>(x, hidden, params, out);
}

// Round 6
// 78.764 us; speedup vs baseline: 1.3006x; 1.0466x over previous
//
#include <hip/hip_runtime.h>
#include <math.h>

#define TSTEPS 48
#define FEAT 60
#define BATCH 128
#define BLOCK 512
#define TWO_PI_F 6.2831853071795864769f

// R15 (resubmit; R5 was an infra failure, kernel never ran).
// Same math as R14 (coef[m][243] monomial recurrence, Phase-C split setup).
//  (1) per-step trig via packed polynomial sin/cos (radians; |h|<=1 since
//      h' = Tr(G_m rho), eig(G_m) = +-1) -- replaces 10 quarter-rate TRANS
//      ops with 18 pk + 9 scalar full-rate FMAs; revolutions scaling dropped.
//  (2) 5-way wave reduction written stage-grouped so the 5 independent DPP
//      chains interleave without hazard stalls.

struct Cf { float r, i; };
__device__ __forceinline__ Cf cmul(Cf a, Cf b){ return {a.r*b.r - a.i*b.i, a.r*b.i + a.i*b.r}; }
__device__ __forceinline__ Cf cadd(Cf a, Cf b){ return {a.r+b.r, a.i+b.i}; }
__device__ __forceinline__ void mm2(const Cf A[4], const Cf B[4], Cf D[4]) {
  D[0] = cadd(cmul(A[0],B[0]), cmul(A[1],B[2]));
  D[1] = cadd(cmul(A[0],B[1]), cmul(A[1],B[3]));
  D[2] = cadd(cmul(A[2],B[0]), cmul(A[3],B[2]));
  D[3] = cadd(cmul(A[2],B[1]), cmul(A[3],B[3]));
}

// fused U = RZ * RY * RX from 3 consecutive params (args in [0,2pi))
__device__ __forceinline__ void fusedU(const float* p, Cf U[4]) {
  float cx = __cosf(0.5f*p[0]), sxn = __sinf(0.5f*p[0]);
  float cy = __cosf(0.5f*p[1]), syn = __sinf(0.5f*p[1]);
  float cz = __cosf(0.5f*p[2]), szn = __sinf(0.5f*p[2]);
  Cf RX[4] = {{cx,0.f},{0.f,-sxn},{0.f,-sxn},{cx,0.f}};
  Cf RY[4] = {{cy,0.f},{-syn,0.f},{syn,0.f},{cy,0.f}};
  Cf RZ[4] = {{cz,-szn},{0.f,0.f},{0.f,0.f},{cz,szn}};
  Cf M[4];
  mm2(RY, RX, M);
  mm2(RZ, M, U);
}

template<int CTRL>
__device__ __forceinline__ float dppf(float v) {
  return __int_as_float(__builtin_amdgcn_mov_dpp(__float_as_int(v), CTRL, 0xF, 0xF, true));
}

template<int M>
__device__ __forceinline__ float sx(float v) {
  if constexpr (M == 1)      return dppf<0xB1>(v);
  else if constexpr (M == 2) return dppf<0x4E>(v);
  else if constexpr (M == 3) return dppf<0x1B>(v);
  else if constexpr (M == 4) return dppf<0x141>(dppf<0x1B>(v));
  else                       return dppf<0x128>(v);   // M == 8
}

template<int M>
__device__ __forceinline__ Cf sxc(Cf v){ return { sx<M>(v.r), sx<M>(v.i) }; }

// ---- packed f32 (VOP3P) ----
typedef float v2f __attribute__((ext_vector_type(2)));
__device__ __forceinline__ v2f pk_fma(v2f a, v2f b, v2f c) {
  v2f d;
  asm("v_pk_fma_f32 %0, %1, %2, %3" : "=v"(d) : "v"(a), "v"(b), "v"(c));
  return d;
}
__device__ __forceinline__ v2f pk_mul(v2f a, v2f b) {
  v2f d;
  asm("v_pk_mul_f32 %0, %1, %2" : "=v"(d) : "v"(a), "v"(b));
  return d;
}

__device__ __forceinline__ float2 conjmul(float2 a, float2 b) {
  return make_float2(a.x*b.x + a.y*b.y, a.x*b.y - a.y*b.x);   // conj(a)*b
}

// ---- V-build gate helpers (4 amps/thread) ----
template<int M>
__device__ __forceinline__ void lane_u(Cf A[4], const Cf U[4], int hi) {
  Cf ca = hi ? U[3] : U[0];
  Cf cb = hi ? U[2] : U[1];
  #pragma unroll
  for (int r = 0; r < 4; ++r) {
    Cf o = sxc<M>(A[r]);
    A[r] = cadd(cmul(ca, A[r]), cmul(cb, o));
  }
}
template<int M>
__device__ __forceinline__ void lane_crx(Cf A[4], float c, float s, int cv) {
  float cc = cv ? c : 1.f, ss = cv ? s : 0.f;
  #pragma unroll
  for (int r = 0; r < 4; ++r) {
    Cf o = sxc<M>(A[r]);
    A[r] = { cc*A[r].r + ss*o.i, cc*A[r].i - ss*o.r };
  }
}
__device__ __forceinline__ void reg_u_b1(Cf A[4], const Cf U[4]) {
  #pragma unroll
  for (int k = 0; k < 2; ++k) {
    Cf a0 = A[k], a1 = A[k+2];
    A[k]   = cadd(cmul(U[0], a0), cmul(U[1], a1));
    A[k+2] = cadd(cmul(U[2], a0), cmul(U[3], a1));
  }
}
__device__ __forceinline__ void reg_u_b0(Cf A[4], const Cf U[4]) {
  #pragma unroll
  for (int k = 0; k < 4; k += 2) {
    Cf a0 = A[k], a1 = A[k+1];
    A[k]   = cadd(cmul(U[0], a0), cmul(U[1], a1));
    A[k+1] = cadd(cmul(U[2], a0), cmul(U[3], a1));
  }
}
__device__ __forceinline__ void reg_crx_b1(Cf A[4], float c, float s, int cv) {
  float cc = cv ? c : 1.f, ss = cv ? s : 0.f;
  #pragma unroll
  for (int k = 0; k < 2; ++k) {
    Cf a0 = A[k], a1 = A[k+2];
    A[k]   = { cc*a0.r + ss*a1.i, cc*a0.i - ss*a1.r };
    A[k+2] = { ss*a0.i + cc*a1.r, -ss*a0.r + cc*a1.i };
  }
}
__device__ __forceinline__ void reg_crx_b0c1(Cf A[4], float c, float s) {
  Cf a0 = A[2], a1 = A[3];
  A[2] = { c*a0.r + s*a1.i, c*a0.i - s*a1.r };
  A[3] = { s*a0.i + c*a1.r, -s*a0.r + c*a1.i };
}

// generic contraction stage over ALL m: peels current LSB qubit with P.
template<int NTs, int D>
__device__ __forceinline__ void stageK(const float2* __restrict__ src,
                                       float2* __restrict__ dst,
                                       const float2* __restrict__ Pq, int tid) {
  const int total = 5*3*NTs*D*D;
  for (int tau = tid; tau < total; tau += BLOCK) {
    int K = tau % D;
    int J = (tau / D) % D;
    int rest = tau / (D*D);
    int t = rest % NTs;
    int s = (rest / NTs) % 3;
    int m = rest / (3*NTs);
    const float2* Sb = src + (m*NTs + t)*(4*D*D);
    const float2* Pm = Pq + s*4;
    float ax = 0.f, ay = 0.f;
    #pragma unroll
    for (int a = 0; a < 2; ++a)
      #pragma unroll
      for (int bb = 0; bb < 2; ++bb) {
        float2 g = Sb[(2*J+a)*(2*D) + (2*K+bb)];
        float2 p = Pm[bb*2 + a];
        ax += g.x*p.x - g.y*p.y;
        ay += g.x*p.y + g.y*p.x;
      }
    dst[tau] = make_float2(ax, ay);
  }
}

__global__ __launch_bounds__(BLOCK)
void qrnn_kernel(const float* __restrict__ x, const float* __restrict__ hin,
                 const float* __restrict__ params, float* __restrict__ out) {
  __shared__ __align__(16) char bufA[30720];
  __shared__ __align__(16) char bufB[23040];
  __shared__ float coefL[5*256];
  __shared__ float2 Pl[5*12];
  __shared__ float2 U2l[5*4];
  __shared__ float crxcl[8], crxsl[8];
  __shared__ float Wl[6*8];

  const int b   = blockIdx.x;
  const int tid = threadIdx.x;

  float2* Vp  = (float2*)bufB;
  float4* Vp4 = (float4*)bufB;
  float2* A1  = (float2*)bufA;
  float2* A2  = (float2*)bufB;
  float2* A3  = (float2*)bufA;
  float2* A4  = (float2*)bufB;

  // ======= Phase A: small fixed tables — one task group per wave ==========
  if (tid < 5) {                                  // wave 0
    int q = tid;
    Cf U1[4]; fusedU(params + 3*q, U1);
    Cf T[4] = {U1[0], {-U1[1].r,-U1[1].i}, U1[2], {-U1[3].r,-U1[3].i}};
    Cf Ud[4] = {{U1[0].r,-U1[0].i},{U1[2].r,-U1[2].i},
                {U1[1].r,-U1[1].i},{U1[3].r,-U1[3].i}};
    Cf Zt[4]; mm2(T, Ud, Zt);
    Cf Ty[4] = {{-U1[1].i, U1[1].r}, {U1[0].i, -U1[0].r},
                {-U1[3].i, U1[3].r}, {U1[2].i, -U1[2].r}};
    Cf Yt[4]; mm2(Ty, Ud, Yt);
    float2* P = Pl + q*12;
    P[0] = make_float2(1.f,0.f); P[1] = make_float2(0.f,0.f);
    P[2] = make_float2(0.f,0.f); P[3] = make_float2(1.f,0.f);
    #pragma unroll
    for (int e = 0; e < 4; ++e) P[4+e] = make_float2(Zt[e].r, Zt[e].i);
    #pragma unroll
    for (int e = 0; e < 4; ++e) P[8+e] = make_float2(-Yt[e].r, -Yt[e].i);
  } else if (tid >= 64 && tid < 69) {             // wave 1
    int q = tid - 64;
    Cf U2[4]; fusedU(params + 37 + 3*q, U2);
    #pragma unroll
    for (int e = 0; e < 4; ++e) U2l[q*4+e] = make_float2(U2[e].r, U2[e].i);
  } else if (tid >= 128 && tid < 136) {           // wave 2
    int i = tid - 128;
    float th = (i < 4) ? params[15 + i] : params[52 + (i - 4)];
    crxcl[i] = __cosf(0.5f*th); crxsl[i] = __sinf(0.5f*th);
  } else if (tid >= 192 && tid < 198) {           // wave 3
    int k = tid - 192;
    Cf Ua[4], Ub[4], W[4];
    fusedU(params + 19 + 3*k, Ua);
    fusedU(params + 56 + 3*k, Ub);
    mm2(Ub, Ua, W);
    #pragma unroll
    for (int e = 0; e < 4; ++e) { Wl[k*8+2*e] = W[e].r; Wl[k*8+2*e+1] = W[e].i; }
  }
  __syncthreads();

  // ============ V build: DPP gate application (threads 0..255) ============
  if (tid < 256) {
    const int quad = tid & 7, col = tid >> 3;
    const int vb2 = quad & 1, vb3 = (quad >> 1) & 1, vb4 = quad >> 2;
    Cf A[4];
    #pragma unroll
    for (int r = 0; r < 4; ++r)
      A[r] = { ((quad<<2)|r) == col ? 1.f : 0.f, 0.f };
    Cf U2g[5][4];
    #pragma unroll
    for (int q = 0; q < 5; ++q)
      #pragma unroll
      for (int e = 0; e < 4; ++e)
        U2g[q][e] = { U2l[q*4+e].x, U2l[q*4+e].y };
    float c_[8], s_[8];
    #pragma unroll
    for (int g = 0; g < 8; ++g) { c_[g] = crxcl[g]; s_[g] = crxsl[g]; }
    lane_crx<2>(A, c_[0], s_[0], vb4);
    lane_crx<1>(A, c_[1], s_[1], vb3);
    reg_crx_b1 (A, c_[2], s_[2], vb2);
    reg_crx_b0c1(A, c_[3], s_[3]);
    lane_u<4>(A, U2g[0], vb4);
    lane_u<2>(A, U2g[1], vb3);
    lane_u<1>(A, U2g[2], vb2);
    reg_u_b1 (A, U2g[3]);
    reg_u_b0 (A, U2g[4]);
    lane_crx<2>(A, c_[4], s_[4], vb4);
    lane_crx<1>(A, c_[5], s_[5], vb3);
    reg_crx_b1 (A, c_[6], s_[6], vb2);
    reg_crx_b0c1(A, c_[7], s_[7]);
    #pragma unroll
    for (int r = 0; r < 4; ++r)
      Vp[((quad<<2)|r)*32 + col] = make_float2(A[r].r, A[r].i);
  }
  __syncthreads();

  // ====== Phase C + stage 1, i-split across halves (linear in G) ==========
  {
    const int jk = tid & 255;
    const int jt = jk >> 4, kt = jk & 15;
    const int half = tid >> 8;
    const int ibase = half << 4;
    float2 Tacc[2][2], Bacc[4][2][2];
    #pragma unroll
    for (int a = 0; a < 2; ++a)
      #pragma unroll
      for (int c2 = 0; c2 < 2; ++c2) {
        Tacc[a][c2] = make_float2(0.f, 0.f);
        #pragma unroll
        for (int mb = 0; mb < 4; ++mb) Bacc[mb][a][c2] = make_float2(0.f, 0.f);
      }
    #pragma unroll
    for (int ii = 0; ii < 16; ++ii) {
      const int i = ibase + ii;
      float4 vj = Vp4[i*16 + jt], vk = Vp4[i*16 + kt];
      float2 vj0{vj.x,vj.y}, vj1{vj.z,vj.w}, vk0{vk.x,vk.y}, vk1{vk.z,vk.w};
      float2 p[2][2] = {{conjmul(vj0,vk0), conjmul(vj0,vk1)},
                        {conjmul(vj1,vk0), conjmul(vj1,vk1)}};
      #pragma unroll
      for (int a = 0; a < 2; ++a)
        #pragma unroll
        for (int c2 = 0; c2 < 2; ++c2) {
          Tacc[a][c2].x += p[a][c2].x; Tacc[a][c2].y += p[a][c2].y;
        }
      #pragma unroll
      for (int mb = 0; mb < 4; ++mb)
        if (ii & (8 >> mb)) {
          #pragma unroll
          for (int a = 0; a < 2; ++a)
            #pragma unroll
            for (int c2 = 0; c2 < 2; ++c2) {
              Bacc[mb][a][c2].x += p[a][c2].x; Bacc[mb][a][c2].y += p[a][c2].y;
            }
        }
    }
    float2 P4[12];
    #pragma unroll
    for (int e = 0; e < 12; ++e) P4[e] = Pl[4*12 + e];
    const float sgn0 = half ? -1.f : 1.f;
    float2 acc[15];
    #pragma unroll
    for (int m = 0; m < 5; ++m) {
      float2 G[2][2];
      #pragma unroll
      for (int a = 0; a < 2; ++a)
        #pragma unroll
        for (int c2 = 0; c2 < 2; ++c2) {
          float2 t = Tacc[a][c2];
          if (m == 0) G[a][c2] = make_float2(sgn0*t.x, sgn0*t.y);
          else {
            float2 bv = Bacc[m-1][a][c2];
            G[a][c2] = make_float2(t.x - 2.f*bv.x, t.y - 2.f*bv.y);
          }
        }
      #pragma unroll
      for (int s = 0; s < 3; ++s) {
        float ax = 0.f, ay = 0.f;
        #pragma unroll
        for (int a = 0; a < 2; ++a)
          #pragma unroll
          for (int bb = 0; bb < 2; ++bb) {
            float2 g = G[a][bb];
            float2 p = P4[s*4 + bb*2 + a];
            ax += g.x*p.x - g.y*p.y;
            ay += g.x*p.y + g.y*p.x;
          }
        acc[m*3 + s] = make_float2(ax, ay);
      }
    }
    if (half) {
      #pragma unroll
      for (int e = 0; e < 15; ++e) A1[e*256 + jk] = acc[e];
    }
    __syncthreads();
    if (!half) {
      #pragma unroll
      for (int e = 0; e < 15; ++e) {
        float2 v = A1[e*256 + jk];
        A1[e*256 + jk] = make_float2(v.x + acc[e].x, v.y + acc[e].y);
      }
    }
  }
  __syncthreads();

  stageK<3, 8>(A1, A2, Pl + 3*12, tid);  __syncthreads();
  stageK<9, 4>(A2, A3, Pl + 2*12, tid);  __syncthreads();
  stageK<27,2>(A3, A4, Pl + 1*12, tid);  __syncthreads();
  // final: peel qubit 0, real part, fold 1/32  (radians basis)
  for (int tau = tid; tau < 5*256; tau += BLOCK) {
    int n = tau & 255, m = tau >> 8;
    float val = 0.f;
    if (n < 243) {
      int t = n % 81, s = n / 81;
      const float2* Sb = A4 + (m*81 + t)*4;
      const float2* Pm = Pl + s*4;
      float ax = 0.f;
      #pragma unroll
      for (int a = 0; a < 2; ++a)
        #pragma unroll
        for (int bb = 0; bb < 2; ++bb) {
          float2 g = Sb[a*2 + bb];
          float2 p = Pm[bb*2 + a];
          ax += g.x*p.x - g.y*p.y;
        }
      val = ax * 0.03125f;
    }
    coefL[tau] = val;
  }
  __syncthreads();

  // ================= main work =============================================
  const int w = tid >> 6, lane = tid & 63;
  if (w == 0) {
    // ---- hidden recurrence: 243-monomial map, packed poly trig ----
    v2f sAp[2][5], sBp[2][5], sCp[2][5], cfp[5][2];
    #pragma unroll
    for (int s = 0; s < 2; ++s) {
      #pragma unroll
      for (int half = 0; half < 2; ++half) {
        int n = (2*s + half)*64 + lane;
        int nn = (n < 243) ? n : 0;
        int d0 = nn/81; int rm = nn - d0*81;
        int d1 = rm/27; rm -= d1*27;
        int d2 = rm/9;  rm -= d2*9;
        int d3 = rm/3;  int d4 = rm - d3*3;
        int dq[5] = {d0, d1, d2, d3, d4};
        #pragma unroll
        for (int q = 0; q < 5; ++q) {
          if (half == 0) {
            sAp[s][q].x = (dq[q] == 0) ? 1.f : 0.f;
            sBp[s][q].x = (dq[q] == 1) ? 1.f : 0.f;
            sCp[s][q].x = (dq[q] == 2) ? 1.f : 0.f;
          } else {
            sAp[s][q].y = (dq[q] == 0) ? 1.f : 0.f;
            sBp[s][q].y = (dq[q] == 1) ? 1.f : 0.f;
            sCp[s][q].y = (dq[q] == 2) ? 1.f : 0.f;
          }
        }
      }
    }
    #pragma unroll
    for (int m = 0; m < 5; ++m) {
      cfp[m][0].x = coefL[m*256 + lane];
      cfp[m][0].y = coefL[m*256 + lane + 64];
      cfp[m][1].x = coefL[m*256 + lane + 128];
      cfp[m][1].y = coefL[m*256 + lane + 192];
    }
    // poly constants (|x| <= ~1.05): sin deg-7, cos deg-8
    const v2f cS5 = {8.33333333e-3f, 8.33333333e-3f};
    const v2f cS7 = {-1.98412698e-4f, -1.98412698e-4f};
    const v2f cS3 = {-0.166666667f, -0.166666667f};
    const v2f cS1 = {1.f, 1.f};
    const v2f cC8 = {2.48015873e-5f, 2.48015873e-5f};
    const v2f cC6 = {-1.38888889e-3f, -1.38888889e-3f};
    const v2f cC4 = {4.16666667e-2f, 4.16666667e-2f};
    const v2f cC2 = {-0.5f, -0.5f};
    const v2f cC0 = {1.f, 1.f};

    const float* hp = hin + b*5;
    float h0 = hp[0], h1 = hp[1], h2 = hp[2], h3 = hp[3], h4 = hp[4];
    #pragma unroll 1
    for (int t = 0; t < TSTEPS; ++t) {
      // ---- packed polynomial sin/cos ----
      v2f x01 = {h0, h1}, x23 = {h2, h3};
      v2f x2a = pk_mul(x01, x01), x2b = pk_mul(x23, x23);
      v2f ps, pc;
      ps = pk_fma(x2a, cS7, cS5); ps = pk_fma(x2a, ps, cS3); ps = pk_fma(x2a, ps, cS1);
      v2f sin01 = pk_mul(x01, ps);
      ps = pk_fma(x2b, cS7, cS5); ps = pk_fma(x2b, ps, cS3); ps = pk_fma(x2b, ps, cS1);
      v2f sin23 = pk_mul(x23, ps);
      pc = pk_fma(x2a, cC8, cC6); pc = pk_fma(x2a, pc, cC4); pc = pk_fma(x2a, pc, cC2);
      v2f cos01 = pk_fma(x2a, pc, cC0);
      pc = pk_fma(x2b, cC8, cC6); pc = pk_fma(x2b, pc, cC4); pc = pk_fma(x2b, pc, cC2);
      v2f cos23 = pk_fma(x2b, pc, cC0);
      float x4s = h4*h4;
      float ps4 = fmaf(x4s, -1.98412698e-4f, 8.33333333e-3f);
      ps4 = fmaf(x4s, ps4, -0.166666667f);
      ps4 = fmaf(x4s, ps4, 1.f);
      float s4 = h4 * ps4;
      float pc4 = fmaf(x4s, 2.48015873e-5f, -1.38888889e-3f);
      pc4 = fmaf(x4s, pc4, 4.16666667e-2f);
      pc4 = fmaf(x4s, pc4, -0.5f);
      float c4 = fmaf(x4s, pc4, 1.f);

      v2f cqp[5], sqp[5];
      cqp[0] = (v2f){cos01.x, cos01.x}; sqp[0] = (v2f){sin01.x, sin01.x};
      cqp[1] = (v2f){cos01.y, cos01.y}; sqp[1] = (v2f){sin01.y, sin01.y};
      cqp[2] = (v2f){cos23.x, cos23.x}; sqp[2] = (v2f){sin23.x, sin23.x};
      cqp[3] = (v2f){cos23.y, cos23.y}; sqp[3] = (v2f){sin23.y, sin23.y};
      cqp[4] = (v2f){c4, c4};           sqp[4] = (v2f){s4, s4};

      v2f monoP[2];
      #pragma unroll
      for (int s = 0; s < 2; ++s) {
        v2f f0 = pk_fma(sBp[s][0], cqp[0], pk_fma(sCp[s][0], sqp[0], sAp[s][0]));
        v2f f1 = pk_fma(sBp[s][1], cqp[1], pk_fma(sCp[s][1], sqp[1], sAp[s][1]));
        v2f f2 = pk_fma(sBp[s][2], cqp[2], pk_fma(sCp[s][2], sqp[2], sAp[s][2]));
        v2f f3 = pk_fma(sBp[s][3], cqp[3], pk_fma(sCp[s][3], sqp[3], sAp[s][3]));
        v2f f4 = pk_fma(sBp[s][4], cqp[4], pk_fma(sCp[s][4], sqp[4], sAp[s][4]));
        monoP[s] = pk_mul(pk_mul(pk_mul(f0, f1), pk_mul(f2, f3)), f4);
      }
      // per-m dots, then stage-grouped 5-way reduction
      float r0, r1, r2, r3, r4;
      {
        v2f t0 = pk_fma(monoP[1], cfp[0][1], pk_mul(monoP[0], cfp[0][0]));
        v2f t1 = pk_fma(monoP[1], cfp[1][1], pk_mul(monoP[0], cfp[1][0]));
        v2f t2 = pk_fma(monoP[1], cfp[2][1], pk_mul(monoP[0], cfp[2][0]));
        v2f t3 = pk_fma(monoP[1], cfp[3][1], pk_mul(monoP[0], cfp[3][0]));
        v2f t4 = pk_fma(monoP[1], cfp[4][1], pk_mul(monoP[0], cfp[4][0]));
        r0 = t0.x + t0.y; r1 = t1.x + t1.y; r2 = t2.x + t2.y;
        r3 = t3.x + t3.y; r4 = t4.x + t4.y;
      }
      r0 += dppf<0x121>(r0); r1 += dppf<0x121>(r1); r2 += dppf<0x121>(r2);
      r3 += dppf<0x121>(r3); r4 += dppf<0x121>(r4);
      r0 += dppf<0x122>(r0); r1 += dppf<0x122>(r1); r2 += dppf<0x122>(r2);
      r3 += dppf<0x122>(r3); r4 += dppf<0x122>(r4);
      r0 += dppf<0x124>(r0); r1 += dppf<0x124>(r1); r2 += dppf<0x124>(r2);
      r3 += dppf<0x124>(r3); r4 += dppf<0x124>(r4);
      r0 += dppf<0x128>(r0); r1 += dppf<0x128>(r1); r2 += dppf<0x128>(r2);
      r3 += dppf<0x128>(r3); r4 += dppf<0x128>(r4);
      r0 += dppf<0x142>(r0); r1 += dppf<0x142>(r1); r2 += dppf<0x142>(r2);
      r3 += dppf<0x142>(r3); r4 += dppf<0x142>(r4);
      r0 += dppf<0x143>(r0); r1 += dppf<0x143>(r1); r2 += dppf<0x143>(r2);
      r3 += dppf<0x143>(r3); r4 += dppf<0x143>(r4);
      h0 = __int_as_float(__builtin_amdgcn_readlane(__float_as_int(r0), 63));
      h1 = __int_as_float(__builtin_amdgcn_readlane(__float_as_int(r1), 63));
      h2 = __int_as_float(__builtin_amdgcn_readlane(__float_as_int(r2), 63));
      h3 = __int_as_float(__builtin_amdgcn_readlane(__float_as_int(r3), 63));
      h4 = __int_as_float(__builtin_amdgcn_readlane(__float_as_int(r4), 63));
    }
    if (lane < 5) {
      float hv = (lane==0) ? h0 : (lane==1) ? h1 : (lane==2) ? h2
               : (lane==3) ? h3 : h4;
      out[BATCH*TSTEPS*6 + b*5 + lane] = hv;
    }
  } else if (w == 1 && lane < TSTEPS) {
    // ---- visible outputs (pure function of x; W precomputed in LDS) ----
    const float* xp = x + (size_t)b*(TSTEPS*FEAT) + lane*FEAT;
    const float4* xp4 = (const float4*)xp;
    float4 vv[15];
    #pragma unroll
    for (int i2 = 0; i2 < 15; ++i2) vv[i2] = xp4[i2];
    float el[60];
    #pragma unroll
    for (int i2 = 0; i2 < 15; ++i2) {
      el[4*i2+0] = vv[i2].x; el[4*i2+1] = vv[i2].y;
      el[4*i2+2] = vv[i2].z; el[4*i2+3] = vv[i2].w;
    }
    float pooled[6];
    #pragma unroll
    for (int k = 0; k < 6; ++k) {
      float s = 0.f;
      #pragma unroll
      for (int f = 0; f < 10; ++f) s += el[k*10 + f];
      pooled[k] = s * 0.1f;
    }
    float mn = pooled[0], mx = pooled[0];
    #pragma unroll
    for (int v2 = 1; v2 < 6; ++v2) {
      mn = fminf(mn, pooled[v2]); mx = fmaxf(mx, pooled[v2]);
    }
    float* op = out + (size_t)b*(TSTEPS*6) + lane*6;
    #pragma unroll
    for (int k = 0; k < 6; ++k) {
      float W0r = Wl[k*8+0], W0i = Wl[k*8+1], W1r = Wl[k*8+2], W1i = Wl[k*8+3];
      float W2r = Wl[k*8+4], W2i = Wl[k*8+5], W3r = Wl[k*8+6], W3i = Wl[k*8+7];
      float ang = TWO_PI_F * (pooled[k] - mn) / (mx - mn + 1e-8f);
      float ch = __cosf(0.5f*ang), sh = __sinf(0.5f*ang);
      float v0r = W0r*ch + W1i*sh, v0i = W0i*ch - W1r*sh;
      float v1r = W2r*ch + W3i*sh, v1i = W2i*ch - W3r*sh;
      op[k] = (v0r*v0r + v0i*v0i) - (v1r*v1r + v1i*v1i);
    }
  }
}

extern "C" void kernel_launch(void* const* d_in, const int* in_sizes, int n_in,
                              void* d_out, int out_size, void* d_ws, size_t ws_size,
                              hipStream_t stream) {
  const float* x      = (const float*)d_in[0];
  const float* hidden = (const float*)d_in[1];
  const float* params = (const float*)d_in[2];
  float* out          = (float*)d_out;
  qrnn_kernel<<<dim3(BATCH), dim3(BLOCK), 0, stream>>>(x, hidden, params, out);
}